// Round 5
// baseline (486.722 us; speedup 1.0000x reference)
//
#include <hip/hip_runtime.h>
#include <hip/hip_bf16.h>
#include <math.h>

#define V_N   6890
#define N_PTS 16384
#define D_IN  700
#define D_INP 704      // padded K for GEMM1
#define D_HID 256
#define D_OUT 283
#define NCHUNK 32
#define CHUNK  216     // ceil(6890/32)
#define GAP_EPS 2e-3f  // d^2 units; fp32 scan error ~1e-5 -> 200x margin

// ws layout (float units; all offsets *4 bytes, 16B aligned)
#define RINV_OFF 0              // V*9 -> 62016
#define KP4_OFF  62016          // V*4 -> 27584
#define KNN_OFF  89600          // 16384
#define CNT_OFF  105984         // 16
#define FLAG_OFF 106000         // 16384
#define PB_OFF   122384         // NCHUNK*N = 524288
#define PB2_OFF  646672         // 524288
#define PIB_OFF  1170960        // 524288
#define WT1_OFF  1695248        // 90112
#define WT2_OFF  1785360        // 32768
#define WT3_OFF  1818128        // 32768
#define X_OFF    1850896        // 5767168
#define H1_OFF   7618064        // 2097152
#define H2_OFF   9715216        // 2097152
// end 11812368 floats ~= 47.2 MB

typedef __attribute__((ext_vector_type(8))) short short8;
typedef __attribute__((ext_vector_type(4))) float f32x4;

__device__ __forceinline__ unsigned short f2bf(float f) {
    unsigned int u = __builtin_bit_cast(unsigned int, f);
    u += 0x7fffu + ((u >> 16) & 1u);   // RNE
    return (unsigned short)(u >> 16);
}

__device__ __forceinline__ void glds16(const void* g, void* l) {
    __builtin_amdgcn_global_load_lds(
        (const __attribute__((address_space(1))) void*)g,
        (__attribute__((address_space(3))) void*)l, 16, 0, 0);
}

// ---------------- merged prep (blocks 0..26) + weight convert (blocks 27+) ----------------
#define PREP_BLOCKS 27
__global__ __launch_bounds__(256) void prep_wconv_kernel(
    const float* __restrict__ trans, const float* __restrict__ keyp,
    float* __restrict__ rinv, float4* __restrict__ kp4,
    const float* __restrict__ W1, const float* __restrict__ W2,
    const float* __restrict__ W3, unsigned short* __restrict__ wt1,
    unsigned short* __restrict__ wt2, unsigned short* __restrict__ wt3,
    int* __restrict__ cnt)
{
    if (blockIdx.x == 0 && threadIdx.x == 0) cnt[0] = 0;   // flag-list counter
    if (blockIdx.x < PREP_BLOCKS) {
        int v = blockIdx.x * 256 + threadIdx.x;
        if (v >= V_N) return;
        float m[16];
#pragma unroll
        for (int i = 0; i < 16; ++i) m[i] = trans[i * V_N + v];

        float i0  =  m[5]*m[10]*m[15] - m[5]*m[11]*m[14] - m[9]*m[6]*m[15] + m[9]*m[7]*m[14] + m[13]*m[6]*m[11] - m[13]*m[7]*m[10];
        float i4  = -m[4]*m[10]*m[15] + m[4]*m[11]*m[14] + m[8]*m[6]*m[15] - m[8]*m[7]*m[14] - m[12]*m[6]*m[11] + m[12]*m[7]*m[10];
        float i8  =  m[4]*m[9]*m[15]  - m[4]*m[11]*m[13] - m[8]*m[5]*m[15] + m[8]*m[7]*m[13] + m[12]*m[5]*m[11] - m[12]*m[7]*m[9];
        float i12 = -m[4]*m[9]*m[14]  + m[4]*m[10]*m[13] + m[8]*m[5]*m[14] - m[8]*m[6]*m[13] - m[12]*m[5]*m[10] + m[12]*m[6]*m[9];
        float i1  = -m[1]*m[10]*m[15] + m[1]*m[11]*m[14] + m[9]*m[2]*m[15] - m[9]*m[3]*m[14] - m[13]*m[2]*m[11] + m[13]*m[3]*m[10];
        float i5  =  m[0]*m[10]*m[15] - m[0]*m[11]*m[14] - m[8]*m[2]*m[15] + m[8]*m[3]*m[14] + m[12]*m[2]*m[11] - m[12]*m[3]*m[10];
        float i9  = -m[0]*m[9]*m[15]  + m[0]*m[11]*m[13] + m[8]*m[1]*m[15] - m[8]*m[3]*m[13] - m[12]*m[1]*m[11] + m[12]*m[3]*m[9];
        float i2  =  m[1]*m[6]*m[15]  - m[1]*m[7]*m[14]  - m[5]*m[2]*m[15] + m[5]*m[3]*m[14] + m[13]*m[2]*m[7]  - m[13]*m[3]*m[6];
        float i6  = -m[0]*m[6]*m[15]  + m[0]*m[7]*m[14]  + m[4]*m[2]*m[15] - m[4]*m[3]*m[14] - m[12]*m[2]*m[7]  + m[12]*m[3]*m[6];
        float i10 =  m[0]*m[5]*m[15]  - m[0]*m[7]*m[13]  - m[4]*m[1]*m[15] + m[4]*m[3]*m[13] + m[12]*m[1]*m[7]  - m[12]*m[3]*m[5];

        float det = m[0]*i0 + m[1]*i4 + m[2]*i8 + m[3]*i12;
        float id = 1.0f / det;
        rinv[v*9+0] = i0*id;  rinv[v*9+1] = i1*id;  rinv[v*9+2] = i2*id;
        rinv[v*9+3] = i4*id;  rinv[v*9+4] = i5*id;  rinv[v*9+5] = i6*id;
        rinv[v*9+6] = i8*id;  rinv[v*9+7] = i9*id;  rinv[v*9+8] = i10*id;

        float kx = keyp[v*3], ky = keyp[v*3+1], kz = keyp[v*3+2];
        kp4[v] = make_float4(kx, ky, kz, kx*kx + ky*ky + kz*kz);
    } else {
        int idx = (blockIdx.x - PREP_BLOCKS) * 256 + threadIdx.x;
        const int N1 = 256 * D_INP;
        const int N2 = 256 * 256;
        if (idx < N1) {
            int n = idx / D_INP, k = idx - n * D_INP;
            float v = (k < D_IN) ? W1[k * 256 + n] : 0.0f;
            wt1[n * D_INP + k] = f2bf(v);
        } else if (idx < N1 + N2) {
            int t = idx - N1;
            int n = t >> 8, k = t & 255;
            wt2[n * 256 + k] = f2bf(W2[k * 256 + n]);
        } else if (idx < N1 + 2 * N2) {
            int t = idx - N1 - N2;
            int n = t >> 8, k = t & 255;
            wt3[n * 256 + k] = f2bf(W3[k * 256 + n]);
        }
    }
}

// ---------------- KNN scan: branchless fp32 (best, idx, second-best) per chunk ----------------
// kp4[j] index is wave-uniform -> compiler emits s_load (scalar pipe broadcast),
// proven by R3's LDS=0/SGPR=48 resource profile. d = |k|^2 - 2 p.k (pp dropped:
// constant per point, ordering-invariant).
__global__ __launch_bounds__(256) void knn_scan_kernel(
    const float* __restrict__ pts, const float4* __restrict__ kp4,
    float* __restrict__ pb, float* __restrict__ pb2, int* __restrict__ pib)
{
    int tid = threadIdx.x;
    int n = blockIdx.x * 256 + tid;
    int c = blockIdx.y;
    int v0 = c * CHUNK;
    int v1 = min(V_N, v0 + CHUNK);

    float px2 = 2.0f * pts[n*6+0], py2 = 2.0f * pts[n*6+1], pz2 = 2.0f * pts[n*6+2];

    float m1 = 1e30f, m2 = 1e30f;
    int bi = 0x7fffffff;

#define KNN_STEP(kk, jj)                                            \
    {                                                               \
        float d = kk.w - (px2*kk.x + py2*kk.y + pz2*kk.z);          \
        bool lt = d < m1;                                           \
        m2 = lt ? m1 : fminf(m2, d);                                \
        bi = lt ? (jj) : bi;                                        \
        m1 = fminf(m1, d);                                          \
    }

    int j = v0;
    for (; j + 4 <= v1; j += 4) {
        float4 k0 = kp4[j], k1 = kp4[j+1], k2 = kp4[j+2], k3 = kp4[j+3];
        KNN_STEP(k0, j); KNN_STEP(k1, j+1); KNN_STEP(k2, j+2); KNN_STEP(k3, j+3);
    }
    for (; j < v1; ++j) {
        float4 k0 = kp4[j];
        KNN_STEP(k0, j);
    }
#undef KNN_STEP

    pb [(size_t)c*N_PTS + n] = m1;
    pb2[(size_t)c*N_PTS + n] = m2;
    pib[(size_t)c*N_PTS + n] = bi;
}

// ---------------- KNN reduce: merge chunks, certify gap, flag ambiguous ----------------
__global__ __launch_bounds__(256) void knn_reduce_kernel(
    const float* __restrict__ pb, const float* __restrict__ pb2,
    const int* __restrict__ pib, int* __restrict__ knn,
    int* __restrict__ cnt, int* __restrict__ flag_list)
{
    int n = blockIdx.x * 256 + threadIdx.x;
    float m1 = 1e30f, m2 = 1e30f;
    int bi = 0x7fffffff;
#pragma unroll
    for (int c = 0; c < NCHUNK; ++c) {
        float b  = pb [(size_t)c*N_PTS + n];
        float b2 = pb2[(size_t)c*N_PTS + n];
        int   i  = pib[(size_t)c*N_PTS + n];
        float mx = fmaxf(m1, b);
        m2 = fminf(fminf(m2, b2), mx);
        bi = (b < m1) ? i : bi;      // ascending c => equal keeps lower chunk
        m1 = fminf(m1, b);
    }
    knn[n] = bi;
    if (m2 - m1 < GAP_EPS) {         // ambiguous: exact kernel will decide
        int s = atomicAdd(cnt, 1);
        flag_list[s] = n;
    }
}

// ---------------- KNN exact: fp64 full rescan for flagged points ----------------
// Formula bit-identical to the verified always-fp64 version (R2), lexicographic
// (d, index) min => same decisions.
__global__ __launch_bounds__(256) void knn_exact_kernel(
    const float* __restrict__ pts, const float4* __restrict__ kp4,
    const int* __restrict__ cnt, const int* __restrict__ flag_list,
    int* __restrict__ knn)
{
    __shared__ double sd[4];
    __shared__ int    si[4];
    int tid = threadIdx.x;
    int lane = tid & 63, w = tid >> 6;
    int total = cnt[0];

    for (int it = blockIdx.x; it < total; it += gridDim.x) {
        int n = flag_list[it];
        double pxd = (double)pts[n*6+0], pyd = (double)pts[n*6+1], pzd = (double)pts[n*6+2];
        double ppd = pxd*pxd + pyd*pyd + pzd*pzd;
        double best = 1e300; int bi = 0x7fffffff;
        for (int j = tid; j < V_N; j += 256) {
            float4 k = kp4[j];
            double kx = (double)k.x, ky = (double)k.y, kz = (double)k.z;
            double d = ppd - 2.0*(pxd*kx + pyd*ky + pzd*kz) + (kx*kx + ky*ky + kz*kz);
            if (d < best || (d == best && j < bi)) { best = d; bi = j; }
        }
#pragma unroll
        for (int off = 32; off >= 1; off >>= 1) {
            double od = __shfl_xor(best, off);
            int    oi = __shfl_xor(bi, off);
            if (od < best || (od == best && oi < bi)) { best = od; bi = oi; }
        }
        if (lane == 0) { sd[w] = best; si[w] = bi; }
        __syncthreads();
        if (tid == 0) {
            for (int q = 1; q < 4; ++q) {
                if (sd[q] < best || (sd[q] == best && si[q] < bi)) { best = sd[q]; bi = si[q]; }
            }
            knn[n] = bi;
        }
        __syncthreads();
    }
}

// ---------------- features: X row (bf16, 704 padded) + direction posenc tail ----------------
__global__ __launch_bounds__(256) void feat_kernel(
    const float* __restrict__ pts, const float* __restrict__ keyp,
    const int* __restrict__ neigh, const float* __restrict__ restp,
    const float* __restrict__ latent, const float* __restrict__ rinv,
    const int* __restrict__ knn, unsigned short* __restrict__ X,
    float* __restrict__ out)
{
    int w = threadIdx.x >> 6;       // wave in block
    int lane = threadIdx.x & 63;
    int n = blockIdx.x * 4 + w;     // point id

    __shared__ float s_vf[4][28];
    __shared__ int   s_vi[4][8];
    __shared__ float s_dir[4][4];

    int k = knn[n];
    float px = pts[n*6+0], py = pts[n*6+1], pz = pts[n*6+2];

    if (lane < 7) {
        int v = neigh[k*7 + lane];
        s_vi[w][lane] = v;
        float dx = px - keyp[v*3+0];
        float dy = py - keyp[v*3+1];
        float dz = pz - keyp[v*3+2];
        s_vf[w][21 + lane] = sqrtf(dx*dx + dy*dy + dz*dz);
    }
    if (lane == 7) {
        float dx = px - keyp[k*3+0];
        float dy = py - keyp[k*3+1];
        float dz = pz - keyp[k*3+2];
        const float* R = &rinv[k*9];
        float d0 = R[0]*dx + R[1]*dy + R[2]*dz;
        float d1 = R[3]*dx + R[4]*dy + R[5]*dz;
        float d2 = R[6]*dx + R[7]*dy + R[8]*dz;
        float nrm = fmaxf(sqrtf(d0*d0 + d1*d1 + d2*d2), 1e-12f);
        s_dir[w][0] = d0/nrm; s_dir[w][1] = d1/nrm; s_dir[w][2] = d2/nrm;
    }
    __syncthreads();
    if (lane < 21) {
        s_vf[w][lane] = restp[s_vi[w][lane/3]*3 + (lane%3)];
    }
    __syncthreads();

    // output tail (fp32): [dir(3), sin f-major (12), cos (12)]
    if (lane < 27) {
        float val;
        if (lane < 3) val = s_dir[w][lane];
        else if (lane < 15) { int t = lane - 3;  val = sinf(s_dir[w][t%3] * (float)(1 << (t/3))); }
        else                { int t = lane - 15; val = cosf(s_dir[w][t%3] * (float)(1 << (t/3))); }
        out[(size_t)n*D_OUT + 256 + lane] = val;
    }

    // X row bf16: [vfeat(28), sin (280), cos (280), lfeat(112), pad(4)=0]
    for (int i = lane; i < D_INP; i += 64) {
        float val;
        if (i < 28) {
            val = s_vf[w][i];
        } else if (i < 308) {
            int t = i - 28;  val = sinf(s_vf[w][t%28] * (float)(1 << (t/28)));
        } else if (i < 588) {
            int t = i - 308; val = cosf(s_vf[w][t%28] * (float)(1 << (t/28)));
        } else if (i < 700) {
            int t = i - 588; val = latent[s_vi[w][t >> 4]*16 + (t & 15)];
        } else {
            val = 0.0f;
        }
        X[(size_t)n*D_INP + i] = f2bf(val);
    }
}

// ---------------- bf16 MFMA GEMM: C = [relu](A @ Wt^T + b) ----------------
__global__ __launch_bounds__(512) void mfma_gemm(
    const unsigned short* __restrict__ A, int lda,
    const unsigned short* __restrict__ Wt, int ldw,
    const float* __restrict__ bias,
    void* __restrict__ Cout, int ldc, int K, int relu_bf16out)
{
    __shared__ unsigned short As[128 * 32];   // [m][k], 8KB
    __shared__ unsigned short Bs[128 * 32];   // [n][k], 8KB

    int t = threadIdx.x;
    int bm = blockIdx.x * 128;
    int bn = blockIdx.y * 128;

    int l = t & 63, w = t >> 6;
    int mbase = (w >> 2) * 64;
    int nbase = (w & 3) * 32;
    int lrow = l & 15;
    int lk = (l >> 4) * 8;

    const char* gA0 = (const char*)(A + (size_t)(bm + (t >> 2)) * lda) + (t & 3) * 16;
    const char* gB0 = (const char*)(Wt + (size_t)(bn + (t >> 2)) * ldw) + (t & 3) * 16;
    char* lA = (char*)As + t * 16;
    char* lB = (char*)Bs + t * 16;

    f32x4 acc[4][2];
#pragma unroll
    for (int i = 0; i < 4; ++i)
#pragma unroll
        for (int j = 0; j < 2; ++j) acc[i][j] = {0.f, 0.f, 0.f, 0.f};

    for (int k0 = 0; k0 < K; k0 += 32) {
        glds16(gA0 + (size_t)k0 * 2, lA);
        glds16(gB0 + (size_t)k0 * 2, lB);
        __syncthreads();

        short8 af[4], bf[2];
#pragma unroll
        for (int mi = 0; mi < 4; ++mi)
            af[mi] = *(const short8*)&As[(mbase + mi * 16 + lrow) * 32 + lk];
#pragma unroll
        for (int ni = 0; ni < 2; ++ni)
            bf[ni] = *(const short8*)&Bs[(nbase + ni * 16 + lrow) * 32 + lk];

#pragma unroll
        for (int mi = 0; mi < 4; ++mi)
#pragma unroll
            for (int ni = 0; ni < 2; ++ni)
                acc[mi][ni] = __builtin_amdgcn_mfma_f32_16x16x32_bf16(
                    af[mi], bf[ni], acc[mi][ni], 0, 0, 0);
        __syncthreads();
    }

    // epilogue: C/D layout col=lane&15, row=(lane>>4)*4+reg
#pragma unroll
    for (int mi = 0; mi < 4; ++mi) {
#pragma unroll
        for (int ni = 0; ni < 2; ++ni) {
            int col = bn + nbase + ni * 16 + (l & 15);
            float bv = bias[col];
#pragma unroll
            for (int r = 0; r < 4; ++r) {
                int row = bm + mbase + mi * 16 + (l >> 4) * 4 + r;
                float val = acc[mi][ni][r] + bv;
                if (relu_bf16out) {
                    val = fmaxf(val, 0.0f);
                    ((unsigned short*)Cout)[(size_t)row * ldc + col] = f2bf(val);
                } else {
                    ((float*)Cout)[(size_t)row * ldc + col] = val;
                }
            }
        }
    }
}

extern "C" void kernel_launch(void* const* d_in, const int* in_sizes, int n_in,
                              void* d_out, int out_size, void* d_ws, size_t ws_size,
                              hipStream_t stream) {
    const float* pts    = (const float*)d_in[0];
    const float* keyp   = (const float*)d_in[1];
    const float* trans  = (const float*)d_in[2];
    const int*   neigh  = (const int*)d_in[3];
    const float* restp  = (const float*)d_in[4];
    const float* latent = (const float*)d_in[5];
    const float* W1     = (const float*)d_in[6];
    const float* b1     = (const float*)d_in[7];
    const float* W2     = (const float*)d_in[8];
    const float* b2     = (const float*)d_in[9];
    const float* W3     = (const float*)d_in[10];
    const float* b3     = (const float*)d_in[11];
    float* out = (float*)d_out;

    float* wsf = (float*)d_ws;
    float*          rinv = wsf + RINV_OFF;
    float4*         kp4  = (float4*)(wsf + KP4_OFF);
    int*            knn  = (int*)(wsf + KNN_OFF);
    int*            cnt  = (int*)(wsf + CNT_OFF);
    int*            flg  = (int*)(wsf + FLAG_OFF);
    float*          pb   = wsf + PB_OFF;
    float*          pb2  = wsf + PB2_OFF;
    int*            pib  = (int*)(wsf + PIB_OFF);
    unsigned short* wt1  = (unsigned short*)(wsf + WT1_OFF);
    unsigned short* wt2  = (unsigned short*)(wsf + WT2_OFF);
    unsigned short* wt3  = (unsigned short*)(wsf + WT3_OFF);
    unsigned short* X    = (unsigned short*)(wsf + X_OFF);
    unsigned short* H1   = (unsigned short*)(wsf + H1_OFF);
    unsigned short* H2   = (unsigned short*)(wsf + H2_OFF);

    int wconv_blocks = (256*D_INP + 2*256*256 + 255) / 256;
    prep_wconv_kernel<<<PREP_BLOCKS + wconv_blocks, 256, 0, stream>>>(
        trans, keyp, rinv, kp4, W1, W2, W3, wt1, wt2, wt3, cnt);
    knn_scan_kernel<<<dim3(N_PTS/256, NCHUNK), 256, 0, stream>>>(pts, kp4, pb, pb2, pib);
    knn_reduce_kernel<<<N_PTS/256, 256, 0, stream>>>(pb, pb2, pib, knn, cnt, flg);
    knn_exact_kernel<<<64, 256, 0, stream>>>(pts, kp4, cnt, flg, knn);
    feat_kernel<<<N_PTS/4, 256, 0, stream>>>(pts, keyp, neigh, restp, latent, rinv,
                                             knn, X, out);

    mfma_gemm<<<dim3(N_PTS/128, 2), 512, 0, stream>>>(X,  D_INP, wt1, D_INP, b1, H1,  256, D_INP, 1);
    mfma_gemm<<<dim3(N_PTS/128, 2), 512, 0, stream>>>(H1, D_HID, wt2, D_HID, b2, H2,  256, D_HID, 1);
    mfma_gemm<<<dim3(N_PTS/128, 2), 512, 0, stream>>>(H2, D_HID, wt3, D_HID, b3, out, D_OUT, D_HID, 0);
}

// Round 6
// 217.361 us; speedup vs baseline: 2.2392x; 2.2392x over previous
//
#include <hip/hip_runtime.h>
#include <hip/hip_bf16.h>
#include <math.h>

#define V_N   6890
#define N_PTS 16384
#define D_IN  700
#define D_INP 704      // padded K for GEMM1
#define D_HID 256
#define D_OUT 283
#define NCHUNK 32
#define CHUNK  216     // ceil(6890/32)
#define GAP_EPS 1e-4f  // combined fp32 error (ours + reference) ~1e-5 -> 10x margin

// ws layout (float units; all offsets *4 bytes, 16B aligned)
#define RINV_OFF 0              // V*9 -> 62016
#define KP4_OFF  62016          // V*4 -> 27584
#define KNN_OFF  89600          // 16384
#define CNT_OFF  105984         // 16
#define FLAG_OFF 106000         // 16384
#define PB_OFF   122384         // NCHUNK*N = 524288
#define PB2_OFF  646672         // 524288
#define PIB_OFF  1170960        // 524288
#define WT1_OFF  1695248        // 90112
#define WT2_OFF  1785360        // 32768
#define WT3_OFF  1818128        // 32768
#define X_OFF    1850896        // 5767168
#define H1_OFF   7618064        // 2097152
#define H2_OFF   9715216        // 2097152
// end 11812368 floats ~= 47.2 MB

typedef __attribute__((ext_vector_type(8))) short short8;
typedef __attribute__((ext_vector_type(4))) float f32x4;

__device__ __forceinline__ unsigned short f2bf(float f) {
    unsigned int u = __builtin_bit_cast(unsigned int, f);
    u += 0x7fffu + ((u >> 16) & 1u);   // RNE
    return (unsigned short)(u >> 16);
}

__device__ __forceinline__ void glds16(const void* g, void* l) {
    __builtin_amdgcn_global_load_lds(
        (const __attribute__((address_space(1))) void*)g,
        (__attribute__((address_space(3))) void*)l, 16, 0, 0);
}

// ---------------- merged prep (blocks 0..26) + weight convert (blocks 27+) ----------------
#define PREP_BLOCKS 27
__global__ __launch_bounds__(256) void prep_wconv_kernel(
    const float* __restrict__ trans, const float* __restrict__ keyp,
    float* __restrict__ rinv, float4* __restrict__ kp4,
    const float* __restrict__ W1, const float* __restrict__ W2,
    const float* __restrict__ W3, unsigned short* __restrict__ wt1,
    unsigned short* __restrict__ wt2, unsigned short* __restrict__ wt3,
    int* __restrict__ cnt)
{
    if (blockIdx.x == 0 && threadIdx.x == 0) cnt[0] = 0;   // flag-list counter
    if (blockIdx.x < PREP_BLOCKS) {
        int v = blockIdx.x * 256 + threadIdx.x;
        if (v >= V_N) return;
        float m[16];
#pragma unroll
        for (int i = 0; i < 16; ++i) m[i] = trans[i * V_N + v];

        float i0  =  m[5]*m[10]*m[15] - m[5]*m[11]*m[14] - m[9]*m[6]*m[15] + m[9]*m[7]*m[14] + m[13]*m[6]*m[11] - m[13]*m[7]*m[10];
        float i4  = -m[4]*m[10]*m[15] + m[4]*m[11]*m[14] + m[8]*m[6]*m[15] - m[8]*m[7]*m[14] - m[12]*m[6]*m[11] + m[12]*m[7]*m[10];
        float i8  =  m[4]*m[9]*m[15]  - m[4]*m[11]*m[13] - m[8]*m[5]*m[15] + m[8]*m[7]*m[13] + m[12]*m[5]*m[11] - m[12]*m[7]*m[9];
        float i12 = -m[4]*m[9]*m[14]  + m[4]*m[10]*m[13] + m[8]*m[5]*m[14] - m[8]*m[6]*m[13] - m[12]*m[5]*m[10] + m[12]*m[6]*m[9];
        float i1  = -m[1]*m[10]*m[15] + m[1]*m[11]*m[14] + m[9]*m[2]*m[15] - m[9]*m[3]*m[14] - m[13]*m[2]*m[11] + m[13]*m[3]*m[10];
        float i5  =  m[0]*m[10]*m[15] - m[0]*m[11]*m[14] - m[8]*m[2]*m[15] + m[8]*m[3]*m[14] + m[12]*m[2]*m[11] - m[12]*m[3]*m[10];
        float i9  = -m[0]*m[9]*m[15]  + m[0]*m[11]*m[13] + m[8]*m[1]*m[15] - m[8]*m[3]*m[13] - m[12]*m[1]*m[11] + m[12]*m[3]*m[9];
        float i2  =  m[1]*m[6]*m[15]  - m[1]*m[7]*m[14]  - m[5]*m[2]*m[15] + m[5]*m[3]*m[14] + m[13]*m[2]*m[7]  - m[13]*m[3]*m[6];
        float i6  = -m[0]*m[6]*m[15]  + m[0]*m[7]*m[14]  + m[4]*m[2]*m[15] - m[4]*m[3]*m[14] - m[12]*m[2]*m[7]  + m[12]*m[3]*m[6];
        float i10 =  m[0]*m[5]*m[15]  - m[0]*m[7]*m[13]  - m[4]*m[1]*m[15] + m[4]*m[3]*m[13] + m[12]*m[1]*m[7]  - m[12]*m[3]*m[5];

        float det = m[0]*i0 + m[1]*i4 + m[2]*i8 + m[3]*i12;
        float id = 1.0f / det;
        rinv[v*9+0] = i0*id;  rinv[v*9+1] = i1*id;  rinv[v*9+2] = i2*id;
        rinv[v*9+3] = i4*id;  rinv[v*9+4] = i5*id;  rinv[v*9+5] = i6*id;
        rinv[v*9+6] = i8*id;  rinv[v*9+7] = i9*id;  rinv[v*9+8] = i10*id;

        float kx = keyp[v*3], ky = keyp[v*3+1], kz = keyp[v*3+2];
        kp4[v] = make_float4(kx, ky, kz, kx*kx + ky*ky + kz*kz);
    } else {
        int idx = (blockIdx.x - PREP_BLOCKS) * 256 + threadIdx.x;
        const int N1 = 256 * D_INP;
        const int N2 = 256 * 256;
        if (idx < N1) {
            int n = idx / D_INP, k = idx - n * D_INP;
            float v = (k < D_IN) ? W1[k * 256 + n] : 0.0f;
            wt1[n * D_INP + k] = f2bf(v);
        } else if (idx < N1 + N2) {
            int t = idx - N1;
            int n = t >> 8, k = t & 255;
            wt2[n * 256 + k] = f2bf(W2[k * 256 + n]);
        } else if (idx < N1 + 2 * N2) {
            int t = idx - N1 - N2;
            int n = t >> 8, k = t & 255;
            wt3[n * 256 + k] = f2bf(W3[k * 256 + n]);
        }
    }
}

// ---------------- KNN scan: branchless fp32 (best, idx, second-best) per chunk ----------------
// kp4[j] index is wave-uniform -> scalar-pipe broadcast loads (R3-proven).
__global__ __launch_bounds__(256) void knn_scan_kernel(
    const float* __restrict__ pts, const float4* __restrict__ kp4,
    float* __restrict__ pb, float* __restrict__ pb2, int* __restrict__ pib)
{
    int tid = threadIdx.x;
    int n = blockIdx.x * 256 + tid;
    int c = blockIdx.y;
    int v0 = c * CHUNK;
    int v1 = min(V_N, v0 + CHUNK);

    float px2 = 2.0f * pts[n*6+0], py2 = 2.0f * pts[n*6+1], pz2 = 2.0f * pts[n*6+2];

    float m1 = 1e30f, m2 = 1e30f;
    int bi = 0x7fffffff;

#define KNN_STEP(kk, jj)                                            \
    {                                                               \
        float d = kk.w - (px2*kk.x + py2*kk.y + pz2*kk.z);          \
        bool lt = d < m1;                                           \
        m2 = lt ? m1 : fminf(m2, d);                                \
        bi = lt ? (jj) : bi;                                        \
        m1 = fminf(m1, d);                                          \
    }

    int j = v0;
    for (; j + 4 <= v1; j += 4) {
        float4 k0 = kp4[j], k1 = kp4[j+1], k2 = kp4[j+2], k3 = kp4[j+3];
        KNN_STEP(k0, j); KNN_STEP(k1, j+1); KNN_STEP(k2, j+2); KNN_STEP(k3, j+3);
    }
    for (; j < v1; ++j) {
        float4 k0 = kp4[j];
        KNN_STEP(k0, j);
    }
#undef KNN_STEP

    pb [(size_t)c*N_PTS + n] = m1;
    pb2[(size_t)c*N_PTS + n] = m2;
    pib[(size_t)c*N_PTS + n] = bi;
}

// ---------------- KNN reduce: merge chunks, certify gap, flag ambiguous ----------------
__global__ __launch_bounds__(256) void knn_reduce_kernel(
    const float* __restrict__ pb, const float* __restrict__ pb2,
    const int* __restrict__ pib, int* __restrict__ knn,
    int* __restrict__ cnt, int* __restrict__ flag_list)
{
    int n = blockIdx.x * 256 + threadIdx.x;
    float m1 = 1e30f, m2 = 1e30f;
    int bi = 0x7fffffff;
#pragma unroll
    for (int c = 0; c < NCHUNK; ++c) {
        float b  = pb [(size_t)c*N_PTS + n];
        float b2 = pb2[(size_t)c*N_PTS + n];
        int   i  = pib[(size_t)c*N_PTS + n];
        float mx = fmaxf(m1, b);
        m2 = fminf(fminf(m2, b2), mx);
        bi = (b < m1) ? i : bi;      // ascending c => equal keeps lower chunk
        m1 = fminf(m1, b);
    }
    knn[n] = bi;
    if (m2 - m1 < GAP_EPS) {         // ambiguous: exact kernel will decide
        int s = atomicAdd(cnt, 1);
        flag_list[s] = n;
    }
}

// ---------------- KNN exact: fp64 rescan, ONE WAVE per flagged point ----------------
// No barriers, no LDS: 64-lane strided scan + shfl_xor butterfly, lexicographic
// (d, index) min -- decision rule bit-identical to the verified fp64 version.
__global__ __launch_bounds__(256) void knn_exact_kernel(
    const float* __restrict__ pts, const float4* __restrict__ kp4,
    const int* __restrict__ cnt, const int* __restrict__ flag_list,
    int* __restrict__ knn)
{
    int lane = threadIdx.x & 63;
    int gwave = (blockIdx.x * 256 + threadIdx.x) >> 6;
    int nwaves = gridDim.x * 4;
    int total = cnt[0];

    for (int it = gwave; it < total; it += nwaves) {
        int n = flag_list[it];
        double pxd = (double)pts[n*6+0], pyd = (double)pts[n*6+1], pzd = (double)pts[n*6+2];
        double ppd = pxd*pxd + pyd*pyd + pzd*pzd;
        double best = 1e300; int bi = 0x7fffffff;
        for (int j = lane; j < V_N; j += 64) {
            float4 k = kp4[j];
            double kx = (double)k.x, ky = (double)k.y, kz = (double)k.z;
            double d = ppd - 2.0*(pxd*kx + pyd*ky + pzd*kz) + (kx*kx + ky*ky + kz*kz);
            if (d < best || (d == best && j < bi)) { best = d; bi = j; }
        }
#pragma unroll
        for (int off = 32; off >= 1; off >>= 1) {
            double od = __shfl_xor(best, off);
            int    oi = __shfl_xor(bi, off);
            if (od < best || (od == best && oi < bi)) { best = od; bi = oi; }
        }
        if (lane == 0) knn[n] = bi;
    }
}

// ---------------- features: X row (bf16, 704 padded) + direction posenc tail ----------------
__global__ __launch_bounds__(256) void feat_kernel(
    const float* __restrict__ pts, const float* __restrict__ keyp,
    const int* __restrict__ neigh, const float* __restrict__ restp,
    const float* __restrict__ latent, const float* __restrict__ rinv,
    const int* __restrict__ knn, unsigned short* __restrict__ X,
    float* __restrict__ out)
{
    int w = threadIdx.x >> 6;       // wave in block
    int lane = threadIdx.x & 63;
    int n = blockIdx.x * 4 + w;     // point id

    __shared__ float s_vf[4][28];
    __shared__ int   s_vi[4][8];
    __shared__ float s_dir[4][4];

    int k = knn[n];
    float px = pts[n*6+0], py = pts[n*6+1], pz = pts[n*6+2];

    if (lane < 7) {
        int v = neigh[k*7 + lane];
        s_vi[w][lane] = v;
        float dx = px - keyp[v*3+0];
        float dy = py - keyp[v*3+1];
        float dz = pz - keyp[v*3+2];
        s_vf[w][21 + lane] = sqrtf(dx*dx + dy*dy + dz*dz);
    }
    if (lane == 7) {
        float dx = px - keyp[k*3+0];
        float dy = py - keyp[k*3+1];
        float dz = pz - keyp[k*3+2];
        const float* R = &rinv[k*9];
        float d0 = R[0]*dx + R[1]*dy + R[2]*dz;
        float d1 = R[3]*dx + R[4]*dy + R[5]*dz;
        float d2 = R[6]*dx + R[7]*dy + R[8]*dz;
        float nrm = fmaxf(sqrtf(d0*d0 + d1*d1 + d2*d2), 1e-12f);
        s_dir[w][0] = d0/nrm; s_dir[w][1] = d1/nrm; s_dir[w][2] = d2/nrm;
    }
    __syncthreads();
    if (lane < 21) {
        s_vf[w][lane] = restp[s_vi[w][lane/3]*3 + (lane%3)];
    }
    __syncthreads();

    // output tail (fp32): [dir(3), sin f-major (12), cos (12)]
    if (lane < 27) {
        float val;
        if (lane < 3) val = s_dir[w][lane];
        else if (lane < 15) { int t = lane - 3;  val = sinf(s_dir[w][t%3] * (float)(1 << (t/3))); }
        else                { int t = lane - 15; val = cosf(s_dir[w][t%3] * (float)(1 << (t/3))); }
        out[(size_t)n*D_OUT + 256 + lane] = val;
    }

    // X row bf16: [vfeat(28), sin (280), cos (280), lfeat(112), pad(4)=0]
    for (int i = lane; i < D_INP; i += 64) {
        float val;
        if (i < 28) {
            val = s_vf[w][i];
        } else if (i < 308) {
            int t = i - 28;  val = sinf(s_vf[w][t%28] * (float)(1 << (t/28)));
        } else if (i < 588) {
            int t = i - 308; val = cosf(s_vf[w][t%28] * (float)(1 << (t/28)));
        } else if (i < 700) {
            int t = i - 588; val = latent[s_vi[w][t >> 4]*16 + (t & 15)];
        } else {
            val = 0.0f;
        }
        X[(size_t)n*D_INP + i] = f2bf(val);
    }
}

// ---------------- bf16 MFMA GEMM: C = [relu](A @ Wt^T + b) ----------------
__global__ __launch_bounds__(512) void mfma_gemm(
    const unsigned short* __restrict__ A, int lda,
    const unsigned short* __restrict__ Wt, int ldw,
    const float* __restrict__ bias,
    void* __restrict__ Cout, int ldc, int K, int relu_bf16out)
{
    __shared__ unsigned short As[128 * 32];   // [m][k], 8KB
    __shared__ unsigned short Bs[128 * 32];   // [n][k], 8KB

    int t = threadIdx.x;
    int bm = blockIdx.x * 128;
    int bn = blockIdx.y * 128;

    int l = t & 63, w = t >> 6;
    int mbase = (w >> 2) * 64;
    int nbase = (w & 3) * 32;
    int lrow = l & 15;
    int lk = (l >> 4) * 8;

    const char* gA0 = (const char*)(A + (size_t)(bm + (t >> 2)) * lda) + (t & 3) * 16;
    const char* gB0 = (const char*)(Wt + (size_t)(bn + (t >> 2)) * ldw) + (t & 3) * 16;
    char* lA = (char*)As + t * 16;
    char* lB = (char*)Bs + t * 16;

    f32x4 acc[4][2];
#pragma unroll
    for (int i = 0; i < 4; ++i)
#pragma unroll
        for (int j = 0; j < 2; ++j) acc[i][j] = {0.f, 0.f, 0.f, 0.f};

    for (int k0 = 0; k0 < K; k0 += 32) {
        glds16(gA0 + (size_t)k0 * 2, lA);
        glds16(gB0 + (size_t)k0 * 2, lB);
        __syncthreads();

        short8 af[4], bf[2];
#pragma unroll
        for (int mi = 0; mi < 4; ++mi)
            af[mi] = *(const short8*)&As[(mbase + mi * 16 + lrow) * 32 + lk];
#pragma unroll
        for (int ni = 0; ni < 2; ++ni)
            bf[ni] = *(const short8*)&Bs[(nbase + ni * 16 + lrow) * 32 + lk];

#pragma unroll
        for (int mi = 0; mi < 4; ++mi)
#pragma unroll
            for (int ni = 0; ni < 2; ++ni)
                acc[mi][ni] = __builtin_amdgcn_mfma_f32_16x16x32_bf16(
                    af[mi], bf[ni], acc[mi][ni], 0, 0, 0);
        __syncthreads();
    }

    // epilogue: C/D layout col=lane&15, row=(lane>>4)*4+reg
#pragma unroll
    for (int mi = 0; mi < 4; ++mi) {
#pragma unroll
        for (int ni = 0; ni < 2; ++ni) {
            int col = bn + nbase + ni * 16 + (l & 15);
            float bv = bias[col];
#pragma unroll
            for (int r = 0; r < 4; ++r) {
                int row = bm + mbase + mi * 16 + (l >> 4) * 4 + r;
                float val = acc[mi][ni][r] + bv;
                if (relu_bf16out) {
                    val = fmaxf(val, 0.0f);
                    ((unsigned short*)Cout)[(size_t)row * ldc + col] = f2bf(val);
                } else {
                    ((float*)Cout)[(size_t)row * ldc + col] = val;
                }
            }
        }
    }
}

extern "C" void kernel_launch(void* const* d_in, const int* in_sizes, int n_in,
                              void* d_out, int out_size, void* d_ws, size_t ws_size,
                              hipStream_t stream) {
    const float* pts    = (const float*)d_in[0];
    const float* keyp   = (const float*)d_in[1];
    const float* trans  = (const float*)d_in[2];
    const int*   neigh  = (const int*)d_in[3];
    const float* restp  = (const float*)d_in[4];
    const float* latent = (const float*)d_in[5];
    const float* W1     = (const float*)d_in[6];
    const float* b1     = (const float*)d_in[7];
    const float* W2     = (const float*)d_in[8];
    const float* b2     = (const float*)d_in[9];
    const float* W3     = (const float*)d_in[10];
    const float* b3     = (const float*)d_in[11];
    float* out = (float*)d_out;

    float* wsf = (float*)d_ws;
    float*          rinv = wsf + RINV_OFF;
    float4*         kp4  = (float4*)(wsf + KP4_OFF);
    int*            knn  = (int*)(wsf + KNN_OFF);
    int*            cnt  = (int*)(wsf + CNT_OFF);
    int*            flg  = (int*)(wsf + FLAG_OFF);
    float*          pb   = wsf + PB_OFF;
    float*          pb2  = wsf + PB2_OFF;
    int*            pib  = (int*)(wsf + PIB_OFF);
    unsigned short* wt1  = (unsigned short*)(wsf + WT1_OFF);
    unsigned short* wt2  = (unsigned short*)(wsf + WT2_OFF);
    unsigned short* wt3  = (unsigned short*)(wsf + WT3_OFF);
    unsigned short* X    = (unsigned short*)(wsf + X_OFF);
    unsigned short* H1   = (unsigned short*)(wsf + H1_OFF);
    unsigned short* H2   = (unsigned short*)(wsf + H2_OFF);

    int wconv_blocks = (256*D_INP + 2*256*256 + 255) / 256;
    prep_wconv_kernel<<<PREP_BLOCKS + wconv_blocks, 256, 0, stream>>>(
        trans, keyp, rinv, kp4, W1, W2, W3, wt1, wt2, wt3, cnt);
    knn_scan_kernel<<<dim3(N_PTS/256, NCHUNK), 256, 0, stream>>>(pts, kp4, pb, pb2, pib);
    knn_reduce_kernel<<<N_PTS/256, 256, 0, stream>>>(pb, pb2, pib, knn, cnt, flg);
    knn_exact_kernel<<<128, 256, 0, stream>>>(pts, kp4, cnt, flg, knn);
    feat_kernel<<<N_PTS/4, 256, 0, stream>>>(pts, keyp, neigh, restp, latent, rinv,
                                             knn, X, out);

    mfma_gemm<<<dim3(N_PTS/128, 2), 512, 0, stream>>>(X,  D_INP, wt1, D_INP, b1, H1,  256, D_INP, 1);
    mfma_gemm<<<dim3(N_PTS/128, 2), 512, 0, stream>>>(H1, D_HID, wt2, D_HID, b2, H2,  256, D_HID, 1);
    mfma_gemm<<<dim3(N_PTS/128, 2), 512, 0, stream>>>(H2, D_HID, wt3, D_HID, b3, out, D_OUT, D_HID, 0);
}

// Round 7
// 209.528 us; speedup vs baseline: 2.3229x; 1.0374x over previous
//
#include <hip/hip_runtime.h>
#include <hip/hip_bf16.h>
#include <math.h>

#define V_N   6890
#define N_PTS 16384
#define D_IN  700
#define D_INP 704      // padded K for layer 1
#define D_HID 256
#define D_OUT 283
#define NCHUNK 32
#define CHUNK  216     // ceil(6890/32)
#define GAP_EPS 1e-4f  // combined fp32 error (ours + reference) ~1e-5 -> 10x margin

// ws layout (float units; all offsets *4 bytes, 16B aligned)
#define RINV_OFF 0              // V*9 -> 62016
#define KP4_OFF  62016          // V*4 -> 27584
#define PB4_OFF  89600          // N*NCHUNK float4 = 2097152 floats
#define WT1_OFF  2186752        // 256*704 bf16 = 90112 floats
#define WT2_OFF  2276864        // 32768
#define WT3_OFF  2309632        // 32768
#define X_OFF    2342400        // 16384*704 bf16 = 5767168 floats
// end 8109568 floats ~= 32.4 MB

typedef __attribute__((ext_vector_type(8))) short short8;
typedef __attribute__((ext_vector_type(4))) float f32x4;

__device__ __forceinline__ unsigned short f2bf(float f) {
    unsigned int u = __builtin_bit_cast(unsigned int, f);
    u += 0x7fffu + ((u >> 16) & 1u);   // RNE
    return (unsigned short)(u >> 16);
}

__device__ __forceinline__ void glds16(const void* g, void* l) {
    __builtin_amdgcn_global_load_lds(
        (const __attribute__((address_space(1))) void*)g,
        (__attribute__((address_space(3))) void*)l, 16, 0, 0);
}

// ---------------- merged prep (blocks 0..26) + weight convert (blocks 27+) ----------------
#define PREP_BLOCKS 27
__global__ __launch_bounds__(256) void prep_wconv_kernel(
    const float* __restrict__ trans, const float* __restrict__ keyp,
    float* __restrict__ rinv, float4* __restrict__ kp4,
    const float* __restrict__ W1, const float* __restrict__ W2,
    const float* __restrict__ W3, unsigned short* __restrict__ wt1,
    unsigned short* __restrict__ wt2, unsigned short* __restrict__ wt3)
{
    if (blockIdx.x < PREP_BLOCKS) {
        int v = blockIdx.x * 256 + threadIdx.x;
        if (v >= V_N) return;
        float m[16];
#pragma unroll
        for (int i = 0; i < 16; ++i) m[i] = trans[i * V_N + v];

        float i0  =  m[5]*m[10]*m[15] - m[5]*m[11]*m[14] - m[9]*m[6]*m[15] + m[9]*m[7]*m[14] + m[13]*m[6]*m[11] - m[13]*m[7]*m[10];
        float i4  = -m[4]*m[10]*m[15] + m[4]*m[11]*m[14] + m[8]*m[6]*m[15] - m[8]*m[7]*m[14] - m[12]*m[6]*m[11] + m[12]*m[7]*m[10];
        float i8  =  m[4]*m[9]*m[15]  - m[4]*m[11]*m[13] - m[8]*m[5]*m[15] + m[8]*m[7]*m[13] + m[12]*m[5]*m[11] - m[12]*m[7]*m[9];
        float i12 = -m[4]*m[9]*m[14]  + m[4]*m[10]*m[13] + m[8]*m[5]*m[14] - m[8]*m[6]*m[13] - m[12]*m[5]*m[10] + m[12]*m[6]*m[9];
        float i1  = -m[1]*m[10]*m[15] + m[1]*m[11]*m[14] + m[9]*m[2]*m[15] - m[9]*m[3]*m[14] - m[13]*m[2]*m[11] + m[13]*m[3]*m[10];
        float i5  =  m[0]*m[10]*m[15] - m[0]*m[11]*m[14] - m[8]*m[2]*m[15] + m[8]*m[3]*m[14] + m[12]*m[2]*m[11] - m[12]*m[3]*m[10];
        float i9  = -m[0]*m[9]*m[15]  + m[0]*m[11]*m[13] + m[8]*m[1]*m[15] - m[8]*m[3]*m[13] - m[12]*m[1]*m[11] + m[12]*m[3]*m[9];
        float i2  =  m[1]*m[6]*m[15]  - m[1]*m[7]*m[14]  - m[5]*m[2]*m[15] + m[5]*m[3]*m[14] + m[13]*m[2]*m[7]  - m[13]*m[3]*m[6];
        float i6  = -m[0]*m[6]*m[15]  + m[0]*m[7]*m[14]  + m[4]*m[2]*m[15] - m[4]*m[3]*m[14] - m[12]*m[2]*m[7]  + m[12]*m[3]*m[6];
        float i10 =  m[0]*m[5]*m[15]  - m[0]*m[7]*m[13]  - m[4]*m[1]*m[15] + m[4]*m[3]*m[13] + m[12]*m[1]*m[7]  - m[12]*m[3]*m[5];

        float det = m[0]*i0 + m[1]*i4 + m[2]*i8 + m[3]*i12;
        float id = 1.0f / det;
        rinv[v*9+0] = i0*id;  rinv[v*9+1] = i1*id;  rinv[v*9+2] = i2*id;
        rinv[v*9+3] = i4*id;  rinv[v*9+4] = i5*id;  rinv[v*9+5] = i6*id;
        rinv[v*9+6] = i8*id;  rinv[v*9+7] = i9*id;  rinv[v*9+8] = i10*id;

        float kx = keyp[v*3], ky = keyp[v*3+1], kz = keyp[v*3+2];
        kp4[v] = make_float4(kx, ky, kz, kx*kx + ky*ky + kz*kz);
    } else {
        int idx = (blockIdx.x - PREP_BLOCKS) * 256 + threadIdx.x;
        const int N1 = 256 * D_INP;
        const int N2 = 256 * 256;
        if (idx < N1) {
            int n = idx / D_INP, k = idx - n * D_INP;
            float v = (k < D_IN) ? W1[k * 256 + n] : 0.0f;
            wt1[n * D_INP + k] = f2bf(v);
        } else if (idx < N1 + N2) {
            int t = idx - N1;
            int n = t >> 8, k = t & 255;
            wt2[n * 256 + k] = f2bf(W2[k * 256 + n]);
        } else if (idx < N1 + 2 * N2) {
            int t = idx - N1 - N2;
            int n = t >> 8, k = t & 255;
            wt3[n * 256 + k] = f2bf(W3[k * 256 + n]);
        }
    }
}

// ---------------- KNN scan: branchless fp32 (best, second, idx), packed float4 ----------------
// kp4[j] index is wave-uniform -> scalar-pipe broadcast loads (R3-proven).
__global__ __launch_bounds__(256) void knn_scan_kernel(
    const float* __restrict__ pts, const float4* __restrict__ kp4,
    float4* __restrict__ pb4)
{
    int tid = threadIdx.x;
    int n = blockIdx.x * 256 + tid;
    int c = blockIdx.y;
    int v0 = c * CHUNK;
    int v1 = min(V_N, v0 + CHUNK);

    float px2 = 2.0f * pts[n*6+0], py2 = 2.0f * pts[n*6+1], pz2 = 2.0f * pts[n*6+2];

    float m1 = 1e30f, m2 = 1e30f;
    int bi = 0x7fffffff;

#define KNN_STEP(kk, jj)                                            \
    {                                                               \
        float d = kk.w - (px2*kk.x + py2*kk.y + pz2*kk.z);          \
        bool lt = d < m1;                                           \
        m2 = lt ? m1 : fminf(m2, d);                                \
        bi = lt ? (jj) : bi;                                        \
        m1 = fminf(m1, d);                                          \
    }

    int j = v0;
    for (; j + 4 <= v1; j += 4) {
        float4 k0 = kp4[j], k1 = kp4[j+1], k2 = kp4[j+2], k3 = kp4[j+3];
        KNN_STEP(k0, j); KNN_STEP(k1, j+1); KNN_STEP(k2, j+2); KNN_STEP(k3, j+3);
    }
    for (; j < v1; ++j) {
        float4 k0 = kp4[j];
        KNN_STEP(k0, j);
    }
#undef KNN_STEP

    pb4[(size_t)n*NCHUNK + c] = make_float4(m1, m2, __int_as_float(bi), 0.0f);
}

// ---------------- features: inline chunk-reduce + rare fp64 exact + X/posenc ----------------
__global__ __launch_bounds__(256) void feat_kernel(
    const float* __restrict__ pts, const float* __restrict__ keyp,
    const int* __restrict__ neigh, const float* __restrict__ restp,
    const float* __restrict__ latent, const float* __restrict__ rinv,
    const float4* __restrict__ pb4, const float4* __restrict__ kp4,
    unsigned short* __restrict__ X, float* __restrict__ out)
{
    int w = threadIdx.x >> 6;       // wave in block
    int lane = threadIdx.x & 63;
    int n = blockIdx.x * 4 + w;     // point id

    __shared__ float s_vf[4][28];
    __shared__ int   s_vi[4][8];
    __shared__ float s_dir[4][4];

    // --- cross-chunk reduce (lanes 0..31 hold chunk partials) ---
    float rm1 = 1e30f, rm2 = 1e30f; int ri = 0x7fffffff;
    if (lane < NCHUNK) {
        float4 P = pb4[(size_t)n*NCHUNK + lane];   // coalesced 16B/lane
        rm1 = P.x; rm2 = P.y; ri = __float_as_int(P.z);
    }
#pragma unroll
    for (int off = 16; off >= 1; off >>= 1) {
        float om1 = __shfl_xor(rm1, off);
        float om2 = __shfl_xor(rm2, off);
        int   oi  = __shfl_xor(ri,  off);
        float nm2 = fminf(fminf(rm2, om2), fmaxf(rm1, om1));
        if (om1 < rm1) ri = oi;      // fp32 ties -> gap 0 -> exact path decides
        rm1 = fminf(rm1, om1);
        rm2 = nm2;
    }
    float fm1 = __shfl(rm1, 0), fm2 = __shfl(rm2, 0);
    int k = __shfl(ri, 0);

    if (fm2 - fm1 < GAP_EPS) {
        // exact fp64 rescan by the whole wave (decision rule identical to the
        // verified always-fp64 version: lexicographic (d, index) min)
        double pxd = (double)pts[n*6+0], pyd = (double)pts[n*6+1], pzd = (double)pts[n*6+2];
        double ppd = pxd*pxd + pyd*pyd + pzd*pzd;
        double best = 1e300; int bie = 0x7fffffff;
        for (int j = lane; j < V_N; j += 64) {
            float4 kk = kp4[j];
            double kx = (double)kk.x, ky = (double)kk.y, kz = (double)kk.z;
            double d = ppd - 2.0*(pxd*kx + pyd*ky + pzd*kz) + (kx*kx + ky*ky + kz*kz);
            if (d < best || (d == best && j < bie)) { best = d; bie = j; }
        }
#pragma unroll
        for (int off = 32; off >= 1; off >>= 1) {
            double od = __shfl_xor(best, off);
            int    oi = __shfl_xor(bie, off);
            if (od < best || (od == best && oi < bie)) { best = od; bie = oi; }
        }
        k = __shfl(bie, 0);
    }

    float px = pts[n*6+0], py = pts[n*6+1], pz = pts[n*6+2];

    if (lane < 7) {
        int v = neigh[k*7 + lane];
        s_vi[w][lane] = v;
        float dx = px - keyp[v*3+0];
        float dy = py - keyp[v*3+1];
        float dz = pz - keyp[v*3+2];
        s_vf[w][21 + lane] = sqrtf(dx*dx + dy*dy + dz*dz);
    }
    if (lane == 7) {
        float dx = px - keyp[k*3+0];
        float dy = py - keyp[k*3+1];
        float dz = pz - keyp[k*3+2];
        const float* R = &rinv[k*9];
        float d0 = R[0]*dx + R[1]*dy + R[2]*dz;
        float d1 = R[3]*dx + R[4]*dy + R[5]*dz;
        float d2 = R[6]*dx + R[7]*dy + R[8]*dz;
        float nrm = fmaxf(sqrtf(d0*d0 + d1*d1 + d2*d2), 1e-12f);
        s_dir[w][0] = d0/nrm; s_dir[w][1] = d1/nrm; s_dir[w][2] = d2/nrm;
    }
    __syncthreads();
    if (lane < 21) {
        s_vf[w][lane] = restp[s_vi[w][lane/3]*3 + (lane%3)];
    }
    __syncthreads();

    // output tail (fp32): [dir(3), sin f-major (12), cos (12)]
    if (lane < 27) {
        float val;
        if (lane < 3) val = s_dir[w][lane];
        else if (lane < 15) { int t = lane - 3;  val = sinf(s_dir[w][t%3] * (float)(1 << (t/3))); }
        else                { int t = lane - 15; val = cosf(s_dir[w][t%3] * (float)(1 << (t/3))); }
        out[(size_t)n*D_OUT + 256 + lane] = val;
    }

    // X row bf16: [vfeat(28), sin (280), cos (280), lfeat(112), pad(4)=0]
    for (int i = lane; i < D_INP; i += 64) {
        float val;
        if (i < 28) {
            val = s_vf[w][i];
        } else if (i < 308) {
            int t = i - 28;  val = sinf(s_vf[w][t%28] * (float)(1 << (t/28)));
        } else if (i < 588) {
            int t = i - 308; val = cosf(s_vf[w][t%28] * (float)(1 << (t/28)));
        } else if (i < 700) {
            int t = i - 588; val = latent[s_vi[w][t >> 4]*16 + (t & 15)];
        } else {
            val = 0.0f;
        }
        X[(size_t)n*D_INP + i] = f2bf(val);
    }
}

// ---------------- fused 3-layer MLP: 64 rows/block through all layers ----------------
// 256 blocks x 512 thr (8 waves). Wave w: rows (w>>2)*32 (2 frags), cols (w&3)*64
// (4 frags). H tiles live in LDS (stride 264 bf16: balanced 8-words/bank for both
// the k-contig b128 fragment reads and the epilogue b16 writes).
#define HLD 264
__global__ __launch_bounds__(512) void mlp_kernel(
    const unsigned short* __restrict__ X,
    const unsigned short* __restrict__ wt1,
    const unsigned short* __restrict__ wt2,
    const unsigned short* __restrict__ wt3,
    const float* __restrict__ b1, const float* __restrict__ b2,
    const float* __restrict__ b3, float* __restrict__ out)
{
    __shared__ unsigned short As[64 * 32];     // 4 KB   A k-chunk [m][k]
    __shared__ unsigned short Ws[256 * 32];    // 16 KB  W k-chunk [n][k]
    __shared__ unsigned short H1[64 * HLD];    // 33 KB
    __shared__ unsigned short H2[64 * HLD];    // 33 KB

    int t = threadIdx.x, l = t & 63, w = t >> 6;
    int bm = blockIdx.x * 64;
    int mbase = (w >> 2) * 32, nbase = (w & 3) * 64;
    int lrow = l & 15, lk = (l >> 4) * 8;
    int col0 = l & 15, rquad = (l >> 4) * 4;

    f32x4 acc[2][4];
    short8 af[2], bf[4];

    // ---------------- layer 1: X[704] @ wt1^T -> relu -> H1 ----------------
#pragma unroll
    for (int mi = 0; mi < 2; ++mi)
#pragma unroll
        for (int ni = 0; ni < 4; ++ni) acc[mi][ni] = {0.f, 0.f, 0.f, 0.f};

    for (int k0 = 0; k0 < D_INP; k0 += 32) {
        if (t < 256)
            glds16(X + (size_t)(bm + (t >> 2)) * D_INP + k0 + (t & 3) * 8,
                   (char*)As + t * 16);
#pragma unroll
        for (int i = 0; i < 2; ++i) {
            int c = i * 512 + t;
            glds16(wt1 + (size_t)(c >> 2) * D_INP + k0 + (c & 3) * 8,
                   (char*)Ws + (size_t)c * 16);
        }
        __syncthreads();
#pragma unroll
        for (int mi = 0; mi < 2; ++mi)
            af[mi] = *(const short8*)&As[(mbase + mi * 16 + lrow) * 32 + lk];
#pragma unroll
        for (int ni = 0; ni < 4; ++ni)
            bf[ni] = *(const short8*)&Ws[(nbase + ni * 16 + lrow) * 32 + lk];
#pragma unroll
        for (int mi = 0; mi < 2; ++mi)
#pragma unroll
            for (int ni = 0; ni < 4; ++ni)
                acc[mi][ni] = __builtin_amdgcn_mfma_f32_16x16x32_bf16(
                    af[mi], bf[ni], acc[mi][ni], 0, 0, 0);
        __syncthreads();
    }
#pragma unroll
    for (int mi = 0; mi < 2; ++mi)
#pragma unroll
        for (int ni = 0; ni < 4; ++ni) {
            int col = nbase + ni * 16 + col0;
            float bv = b1[col];
#pragma unroll
            for (int r = 0; r < 4; ++r) {
                int row = mbase + mi * 16 + rquad + r;
                H1[row * HLD + col] = f2bf(fmaxf(acc[mi][ni][r] + bv, 0.0f));
            }
        }
    __syncthreads();

    // ---------------- layer 2: H1 @ wt2^T -> relu -> H2 ----------------
#pragma unroll
    for (int mi = 0; mi < 2; ++mi)
#pragma unroll
        for (int ni = 0; ni < 4; ++ni) acc[mi][ni] = {0.f, 0.f, 0.f, 0.f};

    for (int k0 = 0; k0 < D_HID; k0 += 32) {
#pragma unroll
        for (int i = 0; i < 2; ++i) {
            int c = i * 512 + t;
            glds16(wt2 + (size_t)(c >> 2) * D_HID + k0 + (c & 3) * 8,
                   (char*)Ws + (size_t)c * 16);
        }
        __syncthreads();
#pragma unroll
        for (int mi = 0; mi < 2; ++mi)
            af[mi] = *(const short8*)&H1[(mbase + mi * 16 + lrow) * HLD + k0 + lk];
#pragma unroll
        for (int ni = 0; ni < 4; ++ni)
            bf[ni] = *(const short8*)&Ws[(nbase + ni * 16 + lrow) * 32 + lk];
#pragma unroll
        for (int mi = 0; mi < 2; ++mi)
#pragma unroll
            for (int ni = 0; ni < 4; ++ni)
                acc[mi][ni] = __builtin_amdgcn_mfma_f32_16x16x32_bf16(
                    af[mi], bf[ni], acc[mi][ni], 0, 0, 0);
        __syncthreads();
    }
#pragma unroll
    for (int mi = 0; mi < 2; ++mi)
#pragma unroll
        for (int ni = 0; ni < 4; ++ni) {
            int col = nbase + ni * 16 + col0;
            float bv = b2[col];
#pragma unroll
            for (int r = 0; r < 4; ++r) {
                int row = mbase + mi * 16 + rquad + r;
                H2[row * HLD + col] = f2bf(fmaxf(acc[mi][ni][r] + bv, 0.0f));
            }
        }
    __syncthreads();

    // ---------------- layer 3: H2 @ wt3^T + b3 -> out (fp32) ----------------
#pragma unroll
    for (int mi = 0; mi < 2; ++mi)
#pragma unroll
        for (int ni = 0; ni < 4; ++ni) acc[mi][ni] = {0.f, 0.f, 0.f, 0.f};

    for (int k0 = 0; k0 < D_HID; k0 += 32) {
#pragma unroll
        for (int i = 0; i < 2; ++i) {
            int c = i * 512 + t;
            glds16(wt3 + (size_t)(c >> 2) * D_HID + k0 + (c & 3) * 8,
                   (char*)Ws + (size_t)c * 16);
        }
        __syncthreads();
#pragma unroll
        for (int mi = 0; mi < 2; ++mi)
            af[mi] = *(const short8*)&H2[(mbase + mi * 16 + lrow) * HLD + k0 + lk];
#pragma unroll
        for (int ni = 0; ni < 4; ++ni)
            bf[ni] = *(const short8*)&Ws[(nbase + ni * 16 + lrow) * 32 + lk];
#pragma unroll
        for (int mi = 0; mi < 2; ++mi)
#pragma unroll
            for (int ni = 0; ni < 4; ++ni)
                acc[mi][ni] = __builtin_amdgcn_mfma_f32_16x16x32_bf16(
                    af[mi], bf[ni], acc[mi][ni], 0, 0, 0);
        __syncthreads();
    }
#pragma unroll
    for (int mi = 0; mi < 2; ++mi)
#pragma unroll
        for (int ni = 0; ni < 4; ++ni) {
            int col = nbase + ni * 16 + col0;
            float bv = b3[col];
#pragma unroll
            for (int r = 0; r < 4; ++r) {
                int row = bm + mbase + mi * 16 + rquad + r;
                out[(size_t)row * D_OUT + col] = acc[mi][ni][r] + bv;
            }
        }
}

extern "C" void kernel_launch(void* const* d_in, const int* in_sizes, int n_in,
                              void* d_out, int out_size, void* d_ws, size_t ws_size,
                              hipStream_t stream) {
    const float* pts    = (const float*)d_in[0];
    const float* keyp   = (const float*)d_in[1];
    const float* trans  = (const float*)d_in[2];
    const int*   neigh  = (const int*)d_in[3];
    const float* restp  = (const float*)d_in[4];
    const float* latent = (const float*)d_in[5];
    const float* W1     = (const float*)d_in[6];
    const float* b1     = (const float*)d_in[7];
    const float* W2     = (const float*)d_in[8];
    const float* b2     = (const float*)d_in[9];
    const float* W3     = (const float*)d_in[10];
    const float* b3     = (const float*)d_in[11];
    float* out = (float*)d_out;

    float* wsf = (float*)d_ws;
    float*          rinv = wsf + RINV_OFF;
    float4*         kp4  = (float4*)(wsf + KP4_OFF);
    float4*         pb4  = (float4*)(wsf + PB4_OFF);
    unsigned short* wt1  = (unsigned short*)(wsf + WT1_OFF);
    unsigned short* wt2  = (unsigned short*)(wsf + WT2_OFF);
    unsigned short* wt3  = (unsigned short*)(wsf + WT3_OFF);
    unsigned short* X    = (unsigned short*)(wsf + X_OFF);

    int wconv_blocks = (256*D_INP + 2*256*256 + 255) / 256;
    prep_wconv_kernel<<<PREP_BLOCKS + wconv_blocks, 256, 0, stream>>>(
        trans, keyp, rinv, kp4, W1, W2, W3, wt1, wt2, wt3);
    knn_scan_kernel<<<dim3(N_PTS/256, NCHUNK), 256, 0, stream>>>(pts, kp4, pb4);
    feat_kernel<<<N_PTS/4, 256, 0, stream>>>(pts, keyp, neigh, restp, latent, rinv,
                                             pb4, kp4, X, out);
    mlp_kernel<<<N_PTS/64, 512, 0, stream>>>(X, wt1, wt2, wt3, b1, b2, b3, out);
}

// Round 8
// 208.078 us; speedup vs baseline: 2.3391x; 1.0070x over previous
//
#include <hip/hip_runtime.h>
#include <hip/hip_bf16.h>
#include <math.h>

#define V_N   6890
#define N_PTS 16384
#define D_IN  700
#define D_INP 704      // padded K for layer 1
#define D_HID 256
#define D_OUT 283
#define NCHUNK 32
#define CHUNK  216     // ceil(6890/32)
#define GAP_EPS 1e-4f  // combined fp32 error (ours + reference) ~1e-5 -> 10x margin

// ws layout (float units; all offsets *4 bytes, 16B aligned)
#define RINV_OFF 0              // V*9 -> 62016
#define KP4_OFF  62016          // V*4 -> 27584
#define PB4_OFF  89600          // N*NCHUNK float4 = 2097152 floats
#define WT1_OFF  2186752        // 256*704 bf16 = 90112 floats
#define WT2_OFF  2276864        // 32768
#define WT3_OFF  2309632        // 32768
#define X_OFF    2342400        // 16384*704 bf16 = 5767168 floats
// end 8109568 floats ~= 32.4 MB

typedef __attribute__((ext_vector_type(8))) short short8;
typedef __attribute__((ext_vector_type(4))) float f32x4;

__device__ __forceinline__ unsigned short f2bf(float f) {
    unsigned int u = __builtin_bit_cast(unsigned int, f);
    u += 0x7fffu + ((u >> 16) & 1u);   // RNE
    return (unsigned short)(u >> 16);
}

// HW transcendental: sin(x) = v_sin_f32(fract(x/2pi)), 3 VALU ops vs ~100 for
// libm. Abs error <= ~4e-4 at the largest posenc args (rev~640) -- 10x below
// the bf16 quantization noise already applied to X.
__device__ __forceinline__ float fsin(float x) {
    return __builtin_amdgcn_sinf(__builtin_amdgcn_fractf(x * 0.15915494309189535f));
}
__device__ __forceinline__ float fcos(float x) {
    return __builtin_amdgcn_cosf(__builtin_amdgcn_fractf(x * 0.15915494309189535f));
}

__device__ __forceinline__ void glds16(const void* g, void* l) {
    __builtin_amdgcn_global_load_lds(
        (const __attribute__((address_space(1))) void*)g,
        (__attribute__((address_space(3))) void*)l, 16, 0, 0);
}

// ---------------- merged prep (blocks 0..26) + weight convert (blocks 27+) ----------------
#define PREP_BLOCKS 27
__global__ __launch_bounds__(256) void prep_wconv_kernel(
    const float* __restrict__ trans, const float* __restrict__ keyp,
    float* __restrict__ rinv, float4* __restrict__ kp4,
    const float* __restrict__ W1, const float* __restrict__ W2,
    const float* __restrict__ W3, unsigned short* __restrict__ wt1,
    unsigned short* __restrict__ wt2, unsigned short* __restrict__ wt3)
{
    if (blockIdx.x < PREP_BLOCKS) {
        int v = blockIdx.x * 256 + threadIdx.x;
        if (v >= V_N) return;
        float m[16];
#pragma unroll
        for (int i = 0; i < 16; ++i) m[i] = trans[i * V_N + v];

        float i0  =  m[5]*m[10]*m[15] - m[5]*m[11]*m[14] - m[9]*m[6]*m[15] + m[9]*m[7]*m[14] + m[13]*m[6]*m[11] - m[13]*m[7]*m[10];
        float i4  = -m[4]*m[10]*m[15] + m[4]*m[11]*m[14] + m[8]*m[6]*m[15] - m[8]*m[7]*m[14] - m[12]*m[6]*m[11] + m[12]*m[7]*m[10];
        float i8  =  m[4]*m[9]*m[15]  - m[4]*m[11]*m[13] - m[8]*m[5]*m[15] + m[8]*m[7]*m[13] + m[12]*m[5]*m[11] - m[12]*m[7]*m[9];
        float i12 = -m[4]*m[9]*m[14]  + m[4]*m[10]*m[13] + m[8]*m[5]*m[14] - m[8]*m[6]*m[13] - m[12]*m[5]*m[10] + m[12]*m[6]*m[9];
        float i1  = -m[1]*m[10]*m[15] + m[1]*m[11]*m[14] + m[9]*m[2]*m[15] - m[9]*m[3]*m[14] - m[13]*m[2]*m[11] + m[13]*m[3]*m[10];
        float i5  =  m[0]*m[10]*m[15] - m[0]*m[11]*m[14] - m[8]*m[2]*m[15] + m[8]*m[3]*m[14] + m[12]*m[2]*m[11] - m[12]*m[3]*m[10];
        float i9  = -m[0]*m[9]*m[15]  + m[0]*m[11]*m[13] + m[8]*m[1]*m[15] - m[8]*m[3]*m[13] - m[12]*m[1]*m[11] + m[12]*m[3]*m[9];
        float i2  =  m[1]*m[6]*m[15]  - m[1]*m[7]*m[14]  - m[5]*m[2]*m[15] + m[5]*m[3]*m[14] + m[13]*m[2]*m[7]  - m[13]*m[3]*m[6];
        float i6  = -m[0]*m[6]*m[15]  + m[0]*m[7]*m[14]  + m[4]*m[2]*m[15] - m[4]*m[3]*m[14] - m[12]*m[2]*m[7]  + m[12]*m[3]*m[6];
        float i10 =  m[0]*m[5]*m[15]  - m[0]*m[7]*m[13]  - m[4]*m[1]*m[15] + m[4]*m[3]*m[13] + m[12]*m[1]*m[7]  - m[12]*m[3]*m[5];

        float det = m[0]*i0 + m[1]*i4 + m[2]*i8 + m[3]*i12;
        float id = 1.0f / det;
        rinv[v*9+0] = i0*id;  rinv[v*9+1] = i1*id;  rinv[v*9+2] = i2*id;
        rinv[v*9+3] = i4*id;  rinv[v*9+4] = i5*id;  rinv[v*9+5] = i6*id;
        rinv[v*9+6] = i8*id;  rinv[v*9+7] = i9*id;  rinv[v*9+8] = i10*id;

        float kx = keyp[v*3], ky = keyp[v*3+1], kz = keyp[v*3+2];
        kp4[v] = make_float4(kx, ky, kz, kx*kx + ky*ky + kz*kz);
    } else {
        int idx = (blockIdx.x - PREP_BLOCKS) * 256 + threadIdx.x;
        const int N1 = 256 * D_INP;
        const int N2 = 256 * 256;
        if (idx < N1) {
            int n = idx / D_INP, k = idx - n * D_INP;
            float v = (k < D_IN) ? W1[k * 256 + n] : 0.0f;
            wt1[n * D_INP + k] = f2bf(v);
        } else if (idx < N1 + N2) {
            int t = idx - N1;
            int n = t >> 8, k = t & 255;
            wt2[n * 256 + k] = f2bf(W2[k * 256 + n]);
        } else if (idx < N1 + 2 * N2) {
            int t = idx - N1 - N2;
            int n = t >> 8, k = t & 255;
            wt3[n * 256 + k] = f2bf(W3[k * 256 + n]);
        }
    }
}

// ---------------- KNN scan: branchless fp32 (best, second, idx), packed float4 ----------------
// kp4[j] index is wave-uniform -> scalar-pipe broadcast loads (R3-proven).
__global__ __launch_bounds__(256) void knn_scan_kernel(
    const float* __restrict__ pts, const float4* __restrict__ kp4,
    float4* __restrict__ pb4)
{
    int tid = threadIdx.x;
    int n = blockIdx.x * 256 + tid;
    int c = blockIdx.y;
    int v0 = c * CHUNK;
    int v1 = min(V_N, v0 + CHUNK);

    float px2 = 2.0f * pts[n*6+0], py2 = 2.0f * pts[n*6+1], pz2 = 2.0f * pts[n*6+2];

    float m1 = 1e30f, m2 = 1e30f;
    int bi = 0x7fffffff;

#define KNN_STEP(kk, jj)                                            \
    {                                                               \
        float d = kk.w - (px2*kk.x + py2*kk.y + pz2*kk.z);          \
        bool lt = d < m1;                                           \
        m2 = lt ? m1 : fminf(m2, d);                                \
        bi = lt ? (jj) : bi;                                        \
        m1 = fminf(m1, d);                                          \
    }

    int j = v0;
    for (; j + 4 <= v1; j += 4) {
        float4 k0 = kp4[j], k1 = kp4[j+1], k2 = kp4[j+2], k3 = kp4[j+3];
        KNN_STEP(k0, j); KNN_STEP(k1, j+1); KNN_STEP(k2, j+2); KNN_STEP(k3, j+3);
    }
    for (; j < v1; ++j) {
        float4 k0 = kp4[j];
        KNN_STEP(k0, j);
    }
#undef KNN_STEP

    pb4[(size_t)n*NCHUNK + c] = make_float4(m1, m2, __int_as_float(bi), 0.0f);
}

// ---------------- features: inline chunk-reduce + rare fp64 exact + X/posenc ----------------
__global__ __launch_bounds__(256) void feat_kernel(
    const float* __restrict__ pts, const float* __restrict__ keyp,
    const int* __restrict__ neigh, const float* __restrict__ restp,
    const float* __restrict__ latent, const float* __restrict__ rinv,
    const float4* __restrict__ pb4, const float4* __restrict__ kp4,
    unsigned short* __restrict__ X, float* __restrict__ out)
{
    int w = threadIdx.x >> 6;       // wave in block
    int lane = threadIdx.x & 63;
    int n = blockIdx.x * 4 + w;     // point id

    __shared__ float s_vf[4][28];
    __shared__ int   s_vi[4][8];
    __shared__ float s_dir[4][4];

    // --- cross-chunk reduce (lanes 0..31 hold chunk partials) ---
    float rm1 = 1e30f, rm2 = 1e30f; int ri = 0x7fffffff;
    if (lane < NCHUNK) {
        float4 P = pb4[(size_t)n*NCHUNK + lane];   // coalesced 16B/lane
        rm1 = P.x; rm2 = P.y; ri = __float_as_int(P.z);
    }
#pragma unroll
    for (int off = 16; off >= 1; off >>= 1) {
        float om1 = __shfl_xor(rm1, off);
        float om2 = __shfl_xor(rm2, off);
        int   oi  = __shfl_xor(ri,  off);
        float nm2 = fminf(fminf(rm2, om2), fmaxf(rm1, om1));
        if (om1 < rm1) ri = oi;      // fp32 ties -> gap 0 -> exact path decides
        rm1 = fminf(rm1, om1);
        rm2 = nm2;
    }
    float fm1 = __shfl(rm1, 0), fm2 = __shfl(rm2, 0);
    int k = __shfl(ri, 0);

    if (fm2 - fm1 < GAP_EPS) {
        // exact fp64 rescan by the whole wave (decision rule identical to the
        // verified always-fp64 version: lexicographic (d, index) min)
        double pxd = (double)pts[n*6+0], pyd = (double)pts[n*6+1], pzd = (double)pts[n*6+2];
        double ppd = pxd*pxd + pyd*pyd + pzd*pzd;
        double best = 1e300; int bie = 0x7fffffff;
        for (int j = lane; j < V_N; j += 64) {
            float4 kk = kp4[j];
            double kx = (double)kk.x, ky = (double)kk.y, kz = (double)kk.z;
            double d = ppd - 2.0*(pxd*kx + pyd*ky + pzd*kz) + (kx*kx + ky*ky + kz*kz);
            if (d < best || (d == best && j < bie)) { best = d; bie = j; }
        }
#pragma unroll
        for (int off = 32; off >= 1; off >>= 1) {
            double od = __shfl_xor(best, off);
            int    oi = __shfl_xor(bie, off);
            if (od < best || (od == best && oi < bie)) { best = od; bie = oi; }
        }
        k = __shfl(bie, 0);
    }

    float px = pts[n*6+0], py = pts[n*6+1], pz = pts[n*6+2];

    if (lane < 7) {
        int v = neigh[k*7 + lane];
        s_vi[w][lane] = v;
        float dx = px - keyp[v*3+0];
        float dy = py - keyp[v*3+1];
        float dz = pz - keyp[v*3+2];
        s_vf[w][21 + lane] = sqrtf(dx*dx + dy*dy + dz*dz);
    }
    if (lane == 7) {
        float dx = px - keyp[k*3+0];
        float dy = py - keyp[k*3+1];
        float dz = pz - keyp[k*3+2];
        const float* R = &rinv[k*9];
        float d0 = R[0]*dx + R[1]*dy + R[2]*dz;
        float d1 = R[3]*dx + R[4]*dy + R[5]*dz;
        float d2 = R[6]*dx + R[7]*dy + R[8]*dz;
        float nrm = fmaxf(sqrtf(d0*d0 + d1*d1 + d2*d2), 1e-12f);
        s_dir[w][0] = d0/nrm; s_dir[w][1] = d1/nrm; s_dir[w][2] = d2/nrm;
    }
    __syncthreads();
    if (lane < 21) {
        s_vf[w][lane] = restp[s_vi[w][lane/3]*3 + (lane%3)];
    }
    __syncthreads();

    // output tail (fp32): [dir(3), sin f-major (12), cos (12)]
    if (lane < 27) {
        float val;
        if (lane < 3) val = s_dir[w][lane];
        else if (lane < 15) { int t = lane - 3;  val = fsin(s_dir[w][t%3] * (float)(1 << (t/3))); }
        else                { int t = lane - 15; val = fcos(s_dir[w][t%3] * (float)(1 << (t/3))); }
        out[(size_t)n*D_OUT + 256 + lane] = val;
    }

    // X row bf16, quad-per-lane (all region boundaries 28/308/588/700/704 are
    // multiples of 4 -> each ushort4 quad is region-uniform): 3 iters, 8B stores
    for (int it = 0; it < 3; ++it) {
        int base = it * 256 + (lane << 2);
        if (base >= D_INP) break;
        unsigned short r0, r1, r2, r3;
        if (base < 28) {
            r0 = f2bf(s_vf[w][base+0]); r1 = f2bf(s_vf[w][base+1]);
            r2 = f2bf(s_vf[w][base+2]); r3 = f2bf(s_vf[w][base+3]);
        } else if (base < 588) {
            bool is_sin = base < 308;
            int t0 = base - (is_sin ? 28 : 308);
            int q = t0 / 28;
            int r = t0 - q * 28;
            float f0 = (float)(1 << q);
            unsigned short rr[4];
#pragma unroll
            for (int j = 0; j < 4; ++j) {
                int rj = r + j; float fj = f0;
                if (rj >= 28) { rj -= 28; fj = f0 * 2.0f; }
                float a = s_vf[w][rj] * fj;
                rr[j] = f2bf(is_sin ? fsin(a) : fcos(a));
            }
            r0 = rr[0]; r1 = rr[1]; r2 = rr[2]; r3 = rr[3];
        } else if (base < 700) {
            int t0 = base - 588;
            int v = s_vi[w][t0 >> 4];
            float4 lv = *(const float4*)&latent[v * 16 + (t0 & 15)];
            r0 = f2bf(lv.x); r1 = f2bf(lv.y); r2 = f2bf(lv.z); r3 = f2bf(lv.w);
        } else {
            r0 = r1 = r2 = r3 = 0;
        }
        ushort4 sv = make_ushort4(r0, r1, r2, r3);
        *(ushort4*)&X[(size_t)n * D_INP + base] = sv;
    }
}

// ---------------- fused 3-layer MLP: 64 rows/block through all layers ----------------
// 256 blocks x 512 thr (8 waves). Wave w: rows (w>>2)*32 (2 frags), cols (w&3)*64
// (4 frags). H tiles live in LDS (stride 264 bf16: balanced 8-words/bank for both
// the k-contig b128 fragment reads and the epilogue b16 writes).
#define HLD 264
__global__ __launch_bounds__(512) void mlp_kernel(
    const unsigned short* __restrict__ X,
    const unsigned short* __restrict__ wt1,
    const unsigned short* __restrict__ wt2,
    const unsigned short* __restrict__ wt3,
    const float* __restrict__ b1, const float* __restrict__ b2,
    const float* __restrict__ b3, float* __restrict__ out)
{
    __shared__ unsigned short As[64 * 32];     // 4 KB   A k-chunk [m][k]
    __shared__ unsigned short Ws[256 * 32];    // 16 KB  W k-chunk [n][k]
    __shared__ unsigned short H1[64 * HLD];    // 33 KB
    __shared__ unsigned short H2[64 * HLD];    // 33 KB

    int t = threadIdx.x, l = t & 63, w = t >> 6;
    int bm = blockIdx.x * 64;
    int mbase = (w >> 2) * 32, nbase = (w & 3) * 64;
    int lrow = l & 15, lk = (l >> 4) * 8;
    int col0 = l & 15, rquad = (l >> 4) * 4;

    f32x4 acc[2][4];
    short8 af[2], bf[4];

    // ---------------- layer 1: X[704] @ wt1^T -> relu -> H1 ----------------
#pragma unroll
    for (int mi = 0; mi < 2; ++mi)
#pragma unroll
        for (int ni = 0; ni < 4; ++ni) acc[mi][ni] = {0.f, 0.f, 0.f, 0.f};

    for (int k0 = 0; k0 < D_INP; k0 += 32) {
        if (t < 256)
            glds16(X + (size_t)(bm + (t >> 2)) * D_INP + k0 + (t & 3) * 8,
                   (char*)As + t * 16);
#pragma unroll
        for (int i = 0; i < 2; ++i) {
            int c = i * 512 + t;
            glds16(wt1 + (size_t)(c >> 2) * D_INP + k0 + (c & 3) * 8,
                   (char*)Ws + (size_t)c * 16);
        }
        __syncthreads();
#pragma unroll
        for (int mi = 0; mi < 2; ++mi)
            af[mi] = *(const short8*)&As[(mbase + mi * 16 + lrow) * 32 + lk];
#pragma unroll
        for (int ni = 0; ni < 4; ++ni)
            bf[ni] = *(const short8*)&Ws[(nbase + ni * 16 + lrow) * 32 + lk];
#pragma unroll
        for (int mi = 0; mi < 2; ++mi)
#pragma unroll
            for (int ni = 0; ni < 4; ++ni)
                acc[mi][ni] = __builtin_amdgcn_mfma_f32_16x16x32_bf16(
                    af[mi], bf[ni], acc[mi][ni], 0, 0, 0);
        __syncthreads();
    }
#pragma unroll
    for (int mi = 0; mi < 2; ++mi)
#pragma unroll
        for (int ni = 0; ni < 4; ++ni) {
            int col = nbase + ni * 16 + col0;
            float bv = b1[col];
#pragma unroll
            for (int r = 0; r < 4; ++r) {
                int row = mbase + mi * 16 + rquad + r;
                H1[row * HLD + col] = f2bf(fmaxf(acc[mi][ni][r] + bv, 0.0f));
            }
        }
    __syncthreads();

    // ---------------- layer 2: H1 @ wt2^T -> relu -> H2 ----------------
#pragma unroll
    for (int mi = 0; mi < 2; ++mi)
#pragma unroll
        for (int ni = 0; ni < 4; ++ni) acc[mi][ni] = {0.f, 0.f, 0.f, 0.f};

    for (int k0 = 0; k0 < D_HID; k0 += 32) {
#pragma unroll
        for (int i = 0; i < 2; ++i) {
            int c = i * 512 + t;
            glds16(wt2 + (size_t)(c >> 2) * D_HID + k0 + (c & 3) * 8,
                   (char*)Ws + (size_t)c * 16);
        }
        __syncthreads();
#pragma unroll
        for (int mi = 0; mi < 2; ++mi)
            af[mi] = *(const short8*)&H1[(mbase + mi * 16 + lrow) * HLD + k0 + lk];
#pragma unroll
        for (int ni = 0; ni < 4; ++ni)
            bf[ni] = *(const short8*)&Ws[(nbase + ni * 16 + lrow) * 32 + lk];
#pragma unroll
        for (int mi = 0; mi < 2; ++mi)
#pragma unroll
            for (int ni = 0; ni < 4; ++ni)
                acc[mi][ni] = __builtin_amdgcn_mfma_f32_16x16x32_bf16(
                    af[mi], bf[ni], acc[mi][ni], 0, 0, 0);
        __syncthreads();
    }
#pragma unroll
    for (int mi = 0; mi < 2; ++mi)
#pragma unroll
        for (int ni = 0; ni < 4; ++ni) {
            int col = nbase + ni * 16 + col0;
            float bv = b2[col];
#pragma unroll
            for (int r = 0; r < 4; ++r) {
                int row = mbase + mi * 16 + rquad + r;
                H2[row * HLD + col] = f2bf(fmaxf(acc[mi][ni][r] + bv, 0.0f));
            }
        }
    __syncthreads();

    // ---------------- layer 3: H2 @ wt3^T + b3 -> out (fp32) ----------------
#pragma unroll
    for (int mi = 0; mi < 2; ++mi)
#pragma unroll
        for (int ni = 0; ni < 4; ++ni) acc[mi][ni] = {0.f, 0.f, 0.f, 0.f};

    for (int k0 = 0; k0 < D_HID; k0 += 32) {
#pragma unroll
        for (int i = 0; i < 2; ++i) {
            int c = i * 512 + t;
            glds16(wt3 + (size_t)(c >> 2) * D_HID + k0 + (c & 3) * 8,
                   (char*)Ws + (size_t)c * 16);
        }
        __syncthreads();
#pragma unroll
        for (int mi = 0; mi < 2; ++mi)
            af[mi] = *(const short8*)&H2[(mbase + mi * 16 + lrow) * HLD + k0 + lk];
#pragma unroll
        for (int ni = 0; ni < 4; ++ni)
            bf[ni] = *(const short8*)&Ws[(nbase + ni * 16 + lrow) * 32 + lk];
#pragma unroll
        for (int mi = 0; mi < 2; ++mi)
#pragma unroll
            for (int ni = 0; ni < 4; ++ni)
                acc[mi][ni] = __builtin_amdgcn_mfma_f32_16x16x32_bf16(
                    af[mi], bf[ni], acc[mi][ni], 0, 0, 0);
        __syncthreads();
    }
#pragma unroll
    for (int mi = 0; mi < 2; ++mi)
#pragma unroll
        for (int ni = 0; ni < 4; ++ni) {
            int col = nbase + ni * 16 + col0;
            float bv = b3[col];
#pragma unroll
            for (int r = 0; r < 4; ++r) {
                int row = bm + mbase + mi * 16 + rquad + r;
                out[(size_t)row * D_OUT + col] = acc[mi][ni][r] + bv;
            }
        }
}

extern "C" void kernel_launch(void* const* d_in, const int* in_sizes, int n_in,
                              void* d_out, int out_size, void* d_ws, size_t ws_size,
                              hipStream_t stream) {
    const float* pts    = (const float*)d_in[0];
    const float* keyp   = (const float*)d_in[1];
    const float* trans  = (const float*)d_in[2];
    const int*   neigh  = (const int*)d_in[3];
    const float* restp  = (const float*)d_in[4];
    const float* latent = (const float*)d_in[5];
    const float* W1     = (const float*)d_in[6];
    const float* b1     = (const float*)d_in[7];
    const float* W2     = (const float*)d_in[8];
    const float* b2     = (const float*)d_in[9];
    const float* W3     = (const float*)d_in[10];
    const float* b3     = (const float*)d_in[11];
    float* out = (float*)d_out;

    float* wsf = (float*)d_ws;
    float*          rinv = wsf + RINV_OFF;
    float4*         kp4  = (float4*)(wsf + KP4_OFF);
    float4*         pb4  = (float4*)(wsf + PB4_OFF);
    unsigned short* wt1  = (unsigned short*)(wsf + WT1_OFF);
    unsigned short* wt2  = (unsigned short*)(wsf + WT2_OFF);
    unsigned short* wt3  = (unsigned short*)(wsf + WT3_OFF);
    unsigned short* X    = (unsigned short*)(wsf + X_OFF);

    int wconv_blocks = (256*D_INP + 2*256*256 + 255) / 256;
    prep_wconv_kernel<<<PREP_BLOCKS + wconv_blocks, 256, 0, stream>>>(
        trans, keyp, rinv, kp4, W1, W2, W3, wt1, wt2, wt3);
    knn_scan_kernel<<<dim3(N_PTS/256, NCHUNK), 256, 0, stream>>>(pts, kp4, pb4);
    feat_kernel<<<N_PTS/4, 256, 0, stream>>>(pts, keyp, neigh, restp, latent, rinv,
                                             pb4, kp4, X, out);
    mlp_kernel<<<N_PTS/64, 512, 0, stream>>>(X, wt1, wt2, wt3, b1, b2, b3, out);
}

// Round 9
// 207.314 us; speedup vs baseline: 2.3478x; 1.0037x over previous
//
#include <hip/hip_runtime.h>
#include <hip/hip_bf16.h>
#include <math.h>

#define V_N   6890
#define N_PTS 16384
#define D_IN  700
#define D_INP 704      // padded K for layer 1
#define D_HID 256
#define D_OUT 283
#define NCHUNK 32
#define CHUNK  216     // ceil(6890/32)
#define GAP_EPS 1e-4f  // combined fp32 error (ours + reference) ~1e-5 -> 10x margin

// ws layout (float units; all offsets *4 bytes, 16B aligned)
#define RINV_OFF 0              // V*9 -> 62016
#define KP4_OFF  62016          // V*4 -> 27584
#define PB4_OFF  89600          // N*NCHUNK float4 = 2097152 floats
#define WT1_OFF  2186752        // 256*704 bf16 = 90112 floats
#define WT2_OFF  2276864        // 32768
#define WT3_OFF  2309632        // 32768
#define X_OFF    2342400        // 16384*704 bf16 = 5767168 floats
// end 8109568 floats ~= 32.4 MB

typedef __attribute__((ext_vector_type(8))) short short8;
typedef __attribute__((ext_vector_type(4))) float f32x4;

__device__ __forceinline__ unsigned short f2bf(float f) {
    unsigned int u = __builtin_bit_cast(unsigned int, f);
    u += 0x7fffu + ((u >> 16) & 1u);   // RNE
    return (unsigned short)(u >> 16);
}

// HW transcendental: sin(x) = v_sin_f32(fract(x/2pi)) -- 3 VALU ops vs ~100 libm.
// Abs error <= ~4e-4 at the largest posenc args -- below bf16 quantization noise.
__device__ __forceinline__ float fsin(float x) {
    return __builtin_amdgcn_sinf(__builtin_amdgcn_fractf(x * 0.15915494309189535f));
}
__device__ __forceinline__ float fcos(float x) {
    return __builtin_amdgcn_cosf(__builtin_amdgcn_fractf(x * 0.15915494309189535f));
}

__device__ __forceinline__ void glds16(const void* g, void* l) {
    __builtin_amdgcn_global_load_lds(
        (const __attribute__((address_space(1))) void*)g,
        (__attribute__((address_space(3))) void*)l, 16, 0, 0);
}

// ---------------- merged prep (blocks 0..26) + weight convert (blocks 27+) ----------------
#define PREP_BLOCKS 27
__global__ __launch_bounds__(256) void prep_wconv_kernel(
    const float* __restrict__ trans, const float* __restrict__ keyp,
    float* __restrict__ rinv, float4* __restrict__ kp4,
    const float* __restrict__ W1, const float* __restrict__ W2,
    const float* __restrict__ W3, unsigned short* __restrict__ wt1,
    unsigned short* __restrict__ wt2, unsigned short* __restrict__ wt3)
{
    if (blockIdx.x < PREP_BLOCKS) {
        int v = blockIdx.x * 256 + threadIdx.x;
        if (v >= V_N) return;
        float m[16];
#pragma unroll
        for (int i = 0; i < 16; ++i) m[i] = trans[i * V_N + v];

        float i0  =  m[5]*m[10]*m[15] - m[5]*m[11]*m[14] - m[9]*m[6]*m[15] + m[9]*m[7]*m[14] + m[13]*m[6]*m[11] - m[13]*m[7]*m[10];
        float i4  = -m[4]*m[10]*m[15] + m[4]*m[11]*m[14] + m[8]*m[6]*m[15] - m[8]*m[7]*m[14] - m[12]*m[6]*m[11] + m[12]*m[7]*m[10];
        float i8  =  m[4]*m[9]*m[15]  - m[4]*m[11]*m[13] - m[8]*m[5]*m[15] + m[8]*m[7]*m[13] + m[12]*m[5]*m[11] - m[12]*m[7]*m[9];
        float i12 = -m[4]*m[9]*m[14]  + m[4]*m[10]*m[13] + m[8]*m[5]*m[14] - m[8]*m[6]*m[13] - m[12]*m[5]*m[10] + m[12]*m[6]*m[9];
        float i1  = -m[1]*m[10]*m[15] + m[1]*m[11]*m[14] + m[9]*m[2]*m[15] - m[9]*m[3]*m[14] - m[13]*m[2]*m[11] + m[13]*m[3]*m[10];
        float i5  =  m[0]*m[10]*m[15] - m[0]*m[11]*m[14] - m[8]*m[2]*m[15] + m[8]*m[3]*m[14] + m[12]*m[2]*m[11] - m[12]*m[3]*m[10];
        float i9  = -m[0]*m[9]*m[15]  + m[0]*m[11]*m[13] + m[8]*m[1]*m[15] - m[8]*m[3]*m[13] - m[12]*m[1]*m[11] + m[12]*m[3]*m[9];
        float i2  =  m[1]*m[6]*m[15]  - m[1]*m[7]*m[14]  - m[5]*m[2]*m[15] + m[5]*m[3]*m[14] + m[13]*m[2]*m[7]  - m[13]*m[3]*m[6];
        float i6  = -m[0]*m[6]*m[15]  + m[0]*m[7]*m[14]  + m[4]*m[2]*m[15] - m[4]*m[3]*m[14] - m[12]*m[2]*m[7]  + m[12]*m[3]*m[6];
        float i10 =  m[0]*m[5]*m[15]  - m[0]*m[7]*m[13]  - m[4]*m[1]*m[15] + m[4]*m[3]*m[13] + m[12]*m[1]*m[7]  - m[12]*m[3]*m[5];

        float det = m[0]*i0 + m[1]*i4 + m[2]*i8 + m[3]*i12;
        float id = 1.0f / det;
        rinv[v*9+0] = i0*id;  rinv[v*9+1] = i1*id;  rinv[v*9+2] = i2*id;
        rinv[v*9+3] = i4*id;  rinv[v*9+4] = i5*id;  rinv[v*9+5] = i6*id;
        rinv[v*9+6] = i8*id;  rinv[v*9+7] = i9*id;  rinv[v*9+8] = i10*id;

        float kx = keyp[v*3], ky = keyp[v*3+1], kz = keyp[v*3+2];
        kp4[v] = make_float4(kx, ky, kz, kx*kx + ky*ky + kz*kz);
    } else {
        int idx = (blockIdx.x - PREP_BLOCKS) * 256 + threadIdx.x;
        const int N1 = 256 * D_INP;
        const int N2 = 256 * 256;
        if (idx < N1) {
            int n = idx / D_INP, k = idx - n * D_INP;
            float v = (k < D_IN) ? W1[k * 256 + n] : 0.0f;
            wt1[n * D_INP + k] = f2bf(v);
        } else if (idx < N1 + N2) {
            int t = idx - N1;
            int n = t >> 8, k = t & 255;
            wt2[n * 256 + k] = f2bf(W2[k * 256 + n]);
        } else if (idx < N1 + 2 * N2) {
            int t = idx - N1 - N2;
            int n = t >> 8, k = t & 255;
            wt3[n * 256 + k] = f2bf(W3[k * 256 + n]);
        }
    }
}

// ---------------- KNN scan: branchless fp32 (best, second, idx), packed float4 ----------------
__global__ __launch_bounds__(256) void knn_scan_kernel(
    const float* __restrict__ pts, const float4* __restrict__ kp4,
    float4* __restrict__ pb4)
{
    int tid = threadIdx.x;
    int n = blockIdx.x * 256 + tid;
    int c = blockIdx.y;
    int v0 = c * CHUNK;
    int v1 = min(V_N, v0 + CHUNK);

    float px2 = 2.0f * pts[n*6+0], py2 = 2.0f * pts[n*6+1], pz2 = 2.0f * pts[n*6+2];

    float m1 = 1e30f, m2 = 1e30f;
    int bi = 0x7fffffff;

#define KNN_STEP(kk, jj)                                            \
    {                                                               \
        float d = kk.w - (px2*kk.x + py2*kk.y + pz2*kk.z);          \
        bool lt = d < m1;                                           \
        m2 = lt ? m1 : fminf(m2, d);                                \
        bi = lt ? (jj) : bi;                                        \
        m1 = fminf(m1, d);                                          \
    }

    int j = v0;
    for (; j + 4 <= v1; j += 4) {
        float4 k0 = kp4[j], k1 = kp4[j+1], k2 = kp4[j+2], k3 = kp4[j+3];
        KNN_STEP(k0, j); KNN_STEP(k1, j+1); KNN_STEP(k2, j+2); KNN_STEP(k3, j+3);
    }
    for (; j < v1; ++j) {
        float4 k0 = kp4[j];
        KNN_STEP(k0, j);
    }
#undef KNN_STEP

    pb4[(size_t)n*NCHUNK + c] = make_float4(m1, m2, __int_as_float(bi), 0.0f);
}

// ---------------- features: barrier-free, LDS-free (all exchange via bpermute) --------
// Every __shfl executes with FULL exec (hoisted out of divergent branches) --
// bpermute from an exec-masked source lane is undefined.
__global__ __launch_bounds__(256) void feat_kernel(
    const float* __restrict__ pts, const float* __restrict__ keyp,
    const int* __restrict__ neigh, const float* __restrict__ restp,
    const float* __restrict__ latent, const float* __restrict__ rinv,
    const float4* __restrict__ pb4, const float4* __restrict__ kp4,
    unsigned short* __restrict__ X, float* __restrict__ out)
{
    int w = threadIdx.x >> 6;       // wave in block
    int lane = threadIdx.x & 63;
    int n = blockIdx.x * 4 + w;     // point id

    float px = pts[n*6+0], py = pts[n*6+1], pz = pts[n*6+2];

    // --- cross-chunk reduce (lanes 0..31 hold chunk partials) ---
    float rm1 = 1e30f, rm2 = 1e30f; int ri = 0x7fffffff;
    if (lane < NCHUNK) {
        float4 P = pb4[(size_t)n*NCHUNK + lane];   // coalesced 16B/lane
        rm1 = P.x; rm2 = P.y; ri = __float_as_int(P.z);
    }
#pragma unroll
    for (int off = 16; off >= 1; off >>= 1) {
        float om1 = __shfl_xor(rm1, off);
        float om2 = __shfl_xor(rm2, off);
        int   oi  = __shfl_xor(ri,  off);
        float nm2 = fminf(fminf(rm2, om2), fmaxf(rm1, om1));
        if (om1 < rm1) ri = oi;      // fp32 ties -> gap 0 -> exact path decides
        rm1 = fminf(rm1, om1);
        rm2 = nm2;
    }
    float fm1 = __shfl(rm1, 0), fm2 = __shfl(rm2, 0);
    int k = __shfl(ri, 0);

    if (fm2 - fm1 < GAP_EPS) {
        // exact fp64 rescan by the whole wave (wave-uniform branch; decision rule
        // identical to the verified always-fp64 version: lexicographic (d, idx) min)
        double pxd = (double)px, pyd = (double)py, pzd = (double)pz;
        double ppd = pxd*pxd + pyd*pyd + pzd*pzd;
        double best = 1e300; int bie = 0x7fffffff;
        for (int j = lane; j < V_N; j += 64) {
            float4 kk = kp4[j];
            double kx = (double)kk.x, ky = (double)kk.y, kz = (double)kk.z;
            double d = ppd - 2.0*(pxd*kx + pyd*ky + pzd*kz) + (kx*kx + ky*ky + kz*kz);
            if (d < best || (d == best && j < bie)) { best = d; bie = j; }
        }
#pragma unroll
        for (int off = 32; off >= 1; off >>= 1) {
            double od = __shfl_xor(best, off);
            int    oi = __shfl_xor(bie, off);
            if (od < best || (od == best && oi < bie)) { best = od; bie = oi; }
        }
        k = __shfl(bie, 0);
    }

    // --- per-lane neighbor data: lanes 0..6 hold (v, dist) ---
    int v7 = 0; float distv = 0.0f;
    if (lane < 7) {
        v7 = neigh[k*7 + lane];
        float dx = px - keyp[v7*3+0];
        float dy = py - keyp[v7*3+1];
        float dz = pz - keyp[v7*3+2];
        distv = sqrtf(dx*dx + dy*dy + dz*dz);
    }

    // --- build the 28-vector vf across lanes 0..27 (full-exec shuffles) ---
    int vr = __shfl(v7, lane < 21 ? lane / 3 : 0);       // full exec
    float rv = 0.0f;
    if (lane < 21) rv = restp[vr*3 + (lane - (lane/3)*3)];
    float dsh = __shfl(distv, (lane >= 21 && lane < 28) ? lane - 21 : 0);  // full exec
    float vf = (lane < 21) ? rv : dsh;

    // --- direction: wave-uniform (k uniform -> scalar loads), computed on all lanes ---
    float ddx = px - keyp[k*3+0];
    float ddy = py - keyp[k*3+1];
    float ddz = pz - keyp[k*3+2];
    const float* R = &rinv[k*9];
    float d0 = R[0]*ddx + R[1]*ddy + R[2]*ddz;
    float d1 = R[3]*ddx + R[4]*ddy + R[5]*ddz;
    float d2 = R[6]*ddx + R[7]*ddy + R[8]*ddz;
    float nrm = fmaxf(sqrtf(d0*d0 + d1*d1 + d2*d2), 1e-12f);
    float dir0 = d0/nrm, dir1 = d1/nrm, dir2 = d2/nrm;

    // output tail (fp32): [dir(3), sin f-major (12), cos (12)] -- no shuffles inside
    if (lane < 27) {
        float val;
        if (lane < 3) {
            val = (lane == 0) ? dir0 : (lane == 1) ? dir1 : dir2;
        } else {
            int t = (lane < 15) ? lane - 3 : lane - 15;
            int m = t % 3;
            float db = (m == 0) ? dir0 : (m == 1) ? dir1 : dir2;
            float a = db * (float)(1 << (t/3));
            val = (lane < 15) ? fsin(a) : fcos(a);
        }
        out[(size_t)n*D_OUT + 256 + lane] = val;
    }

    // --- X row bf16, quad-per-lane; shuffles hoisted to full-exec ---
#pragma unroll
    for (int it = 0; it < 3; ++it) {
        int base = it * 256 + (lane << 2);
        bool in_range = base < D_INP;
        int region = (base < 28) ? 0 : (base < 308) ? 1 : (base < 588) ? 2
                   : (base < 700) ? 3 : 4;

        // vf-shuffle sources for regions 0..2 (dummy otherwise), full exec
        int t0 = (region == 1) ? base - 28 : (region == 2) ? base - 308 : 0;
        int q = t0 / 28;
        int r = t0 - q * 28;
        float f0 = (float)(1 << q);
        float a[4];
#pragma unroll
        for (int j = 0; j < 4; ++j) {
            int rj; float fj;
            if (region == 0) { rj = base + j; fj = 1.0f; }
            else if (region <= 2) {
                rj = r + j; fj = f0;
                if (rj >= 28) { rj -= 28; fj = f0 * 2.0f; }
            } else { rj = 0; fj = 0.0f; }
            a[j] = __shfl(vf, rj) * fj;            // FULL-EXEC bpermute
        }
        int vL = __shfl(v7, (region == 3) ? (base - 588) >> 4 : 0);  // full exec

        unsigned short r0, r1, r2, r3;
        if (region == 0) {
            r0 = f2bf(a[0]); r1 = f2bf(a[1]); r2 = f2bf(a[2]); r3 = f2bf(a[3]);
        } else if (region == 1) {
            r0 = f2bf(fsin(a[0])); r1 = f2bf(fsin(a[1]));
            r2 = f2bf(fsin(a[2])); r3 = f2bf(fsin(a[3]));
        } else if (region == 2) {
            r0 = f2bf(fcos(a[0])); r1 = f2bf(fcos(a[1]));
            r2 = f2bf(fcos(a[2])); r3 = f2bf(fcos(a[3]));
        } else if (region == 3) {
            int t3 = base - 588;
            float4 lv = *(const float4*)&latent[vL * 16 + (t3 & 15)];
            r0 = f2bf(lv.x); r1 = f2bf(lv.y); r2 = f2bf(lv.z); r3 = f2bf(lv.w);
        } else {
            r0 = r1 = r2 = r3 = 0;
        }
        if (in_range)
            *(ushort4*)&X[(size_t)n * D_INP + base] = make_ushort4(r0, r1, r2, r3);
    }
}

// ---------------- fused 3-layer MLP: 64 rows/block through all layers ----------------
#define HLD 264
__global__ __launch_bounds__(512) void mlp_kernel(
    const unsigned short* __restrict__ X,
    const unsigned short* __restrict__ wt1,
    const unsigned short* __restrict__ wt2,
    const unsigned short* __restrict__ wt3,
    const float* __restrict__ b1, const float* __restrict__ b2,
    const float* __restrict__ b3, float* __restrict__ out)
{
    __shared__ unsigned short As[64 * 32];     // 4 KB   A k-chunk [m][k]
    __shared__ unsigned short Ws[256 * 32];    // 16 KB  W k-chunk [n][k]
    __shared__ unsigned short H1[64 * HLD];    // 33 KB
    __shared__ unsigned short H2[64 * HLD];    // 33 KB

    int t = threadIdx.x, l = t & 63, w = t >> 6;
    int bm = blockIdx.x * 64;
    int mbase = (w >> 2) * 32, nbase = (w & 3) * 64;
    int lrow = l & 15, lk = (l >> 4) * 8;
    int col0 = l & 15, rquad = (l >> 4) * 4;

    f32x4 acc[2][4];
    short8 af[2], bf[4];

    // ---------------- layer 1: X[704] @ wt1^T -> relu -> H1 ----------------
#pragma unroll
    for (int mi = 0; mi < 2; ++mi)
#pragma unroll
        for (int ni = 0; ni < 4; ++ni) acc[mi][ni] = {0.f, 0.f, 0.f, 0.f};

    for (int k0 = 0; k0 < D_INP; k0 += 32) {
        if (t < 256)
            glds16(X + (size_t)(bm + (t >> 2)) * D_INP + k0 + (t & 3) * 8,
                   (char*)As + t * 16);
#pragma unroll
        for (int i = 0; i < 2; ++i) {
            int c = i * 512 + t;
            glds16(wt1 + (size_t)(c >> 2) * D_INP + k0 + (c & 3) * 8,
                   (char*)Ws + (size_t)c * 16);
        }
        __syncthreads();
#pragma unroll
        for (int mi = 0; mi < 2; ++mi)
            af[mi] = *(const short8*)&As[(mbase + mi * 16 + lrow) * 32 + lk];
#pragma unroll
        for (int ni = 0; ni < 4; ++ni)
            bf[ni] = *(const short8*)&Ws[(nbase + ni * 16 + lrow) * 32 + lk];
#pragma unroll
        for (int mi = 0; mi < 2; ++mi)
#pragma unroll
            for (int ni = 0; ni < 4; ++ni)
                acc[mi][ni] = __builtin_amdgcn_mfma_f32_16x16x32_bf16(
                    af[mi], bf[ni], acc[mi][ni], 0, 0, 0);
        __syncthreads();
    }
#pragma unroll
    for (int mi = 0; mi < 2; ++mi)
#pragma unroll
        for (int ni = 0; ni < 4; ++ni) {
            int col = nbase + ni * 16 + col0;
            float bv = b1[col];
#pragma unroll
            for (int r = 0; r < 4; ++r) {
                int row = mbase + mi * 16 + rquad + r;
                H1[row * HLD + col] = f2bf(fmaxf(acc[mi][ni][r] + bv, 0.0f));
            }
        }
    __syncthreads();

    // ---------------- layer 2: H1 @ wt2^T -> relu -> H2 ----------------
#pragma unroll
    for (int mi = 0; mi < 2; ++mi)
#pragma unroll
        for (int ni = 0; ni < 4; ++ni) acc[mi][ni] = {0.f, 0.f, 0.f, 0.f};

    for (int k0 = 0; k0 < D_HID; k0 += 32) {
#pragma unroll
        for (int i = 0; i < 2; ++i) {
            int c = i * 512 + t;
            glds16(wt2 + (size_t)(c >> 2) * D_HID + k0 + (c & 3) * 8,
                   (char*)Ws + (size_t)c * 16);
        }
        __syncthreads();
#pragma unroll
        for (int mi = 0; mi < 2; ++mi)
            af[mi] = *(const short8*)&H1[(mbase + mi * 16 + lrow) * HLD + k0 + lk];
#pragma unroll
        for (int ni = 0; ni < 4; ++ni)
            bf[ni] = *(const short8*)&Ws[(nbase + ni * 16 + lrow) * 32 + lk];
#pragma unroll
        for (int mi = 0; mi < 2; ++mi)
#pragma unroll
            for (int ni = 0; ni < 4; ++ni)
                acc[mi][ni] = __builtin_amdgcn_mfma_f32_16x16x32_bf16(
                    af[mi], bf[ni], acc[mi][ni], 0, 0, 0);
        __syncthreads();
    }
#pragma unroll
    for (int mi = 0; mi < 2; ++mi)
#pragma unroll
        for (int ni = 0; ni < 4; ++ni) {
            int col = nbase + ni * 16 + col0;
            float bv = b2[col];
#pragma unroll
            for (int r = 0; r < 4; ++r) {
                int row = mbase + mi * 16 + rquad + r;
                H2[row * HLD + col] = f2bf(fmaxf(acc[mi][ni][r] + bv, 0.0f));
            }
        }
    __syncthreads();

    // ---------------- layer 3: H2 @ wt3^T + b3 -> out (fp32) ----------------
#pragma unroll
    for (int mi = 0; mi < 2; ++mi)
#pragma unroll
        for (int ni = 0; ni < 4; ++ni) acc[mi][ni] = {0.f, 0.f, 0.f, 0.f};

    for (int k0 = 0; k0 < D_HID; k0 += 32) {
#pragma unroll
        for (int i = 0; i < 2; ++i) {
            int c = i * 512 + t;
            glds16(wt3 + (size_t)(c >> 2) * D_HID + k0 + (c & 3) * 8,
                   (char*)Ws + (size_t)c * 16);
        }
        __syncthreads();
#pragma unroll
        for (int mi = 0; mi < 2; ++mi)
            af[mi] = *(const short8*)&H2[(mbase + mi * 16 + lrow) * HLD + k0 + lk];
#pragma unroll
        for (int ni = 0; ni < 4; ++ni)
            bf[ni] = *(const short8*)&Ws[(nbase + ni * 16 + lrow) * 32 + lk];
#pragma unroll
        for (int mi = 0; mi < 2; ++mi)
#pragma unroll
            for (int ni = 0; ni < 4; ++ni)
                acc[mi][ni] = __builtin_amdgcn_mfma_f32_16x16x32_bf16(
                    af[mi], bf[ni], acc[mi][ni], 0, 0, 0);
        __syncthreads();
    }
#pragma unroll
    for (int mi = 0; mi < 2; ++mi)
#pragma unroll
        for (int ni = 0; ni < 4; ++ni) {
            int col = nbase + ni * 16 + col0;
            float bv = b3[col];
#pragma unroll
            for (int r = 0; r < 4; ++r) {
                int row = bm + mbase + mi * 16 + rquad + r;
                out[(size_t)row * D_OUT + col] = acc[mi][ni][r] + bv;
            }
        }
}

extern "C" void kernel_launch(void* const* d_in, const int* in_sizes, int n_in,
                              void* d_out, int out_size, void* d_ws, size_t ws_size,
                              hipStream_t stream) {
    const float* pts    = (const float*)d_in[0];
    const float* keyp   = (const float*)d_in[1];
    const float* trans  = (const float*)d_in[2];
    const int*   neigh  = (const int*)d_in[3];
    const float* restp  = (const float*)d_in[4];
    const float* latent = (const float*)d_in[5];
    const float* W1     = (const float*)d_in[6];
    const float* b1     = (const float*)d_in[7];
    const float* W2     = (const float*)d_in[8];
    const float* b2     = (const float*)d_in[9];
    const float* W3     = (const float*)d_in[10];
    const float* b3     = (const float*)d_in[11];
    float* out = (float*)d_out;

    float* wsf = (float*)d_ws;
    float*          rinv = wsf + RINV_OFF;
    float4*         kp4  = (float4*)(wsf + KP4_OFF);
    float4*         pb4  = (float4*)(wsf + PB4_OFF);
    unsigned short* wt1  = (unsigned short*)(wsf + WT1_OFF);
    unsigned short* wt2  = (unsigned short*)(wsf + WT2_OFF);
    unsigned short* wt3  = (unsigned short*)(wsf + WT3_OFF);
    unsigned short* X    = (unsigned short*)(wsf + X_OFF);

    int wconv_blocks = (256*D_INP + 2*256*256 + 255) / 256;
    prep_wconv_kernel<<<PREP_BLOCKS + wconv_blocks, 256, 0, stream>>>(
        trans, keyp, rinv, kp4, W1, W2, W3, wt1, wt2, wt3);
    knn_scan_kernel<<<dim3(N_PTS/256, NCHUNK), 256, 0, stream>>>(pts, kp4, pb4);
    feat_kernel<<<N_PTS/4, 256, 0, stream>>>(pts, keyp, neigh, restp, latent, rinv,
                                             pb4, kp4, X, out);
    mlp_kernel<<<N_PTS/64, 512, 0, stream>>>(X, wt1, wt2, wt3, b1, b2, b3, out);
}